// Round 1
// baseline (1170.105 us; speedup 1.0000x reference)
//
#include <hip/hip_runtime.h>
#include <math.h>

// VQ-VAE eval forward: z [4,2048,512] f32, W [8192,512] f32.
// Outputs (flat f32): quantized [4194304], indices [8192], loss [1], perplexity [1].

constexpr int N_ROWS = 8192;   // 4*2048
constexpr int K_CODES = 8192;
constexpr int D_DIM = 512;
constexpr int SPLITK = 8;
constexpr int KSPL = K_CODES / SPLITK;  // 1024 codes per split
constexpr int BN = 64, BK = 64, BD = 32;
constexpr float COMMIT = 0.25f;

// workspace layout (float offsets)
constexpr size_t OFF_LOSS   = 0;
constexpr size_t OFF_COUNTS = 64;          // 8192 floats
constexpr size_t OFF_ZZ     = 16384;       // 8192 floats
constexpr size_t OFF_WW     = 24576;       // 8192 floats
constexpr size_t OFF_BESTD  = 32768;       // SPLITK*N = 65536 floats
constexpr size_t OFF_BESTI  = 98304;       // SPLITK*N = 65536 ints
// total = 163840 * 4B = 640 KB of ws

// ---- row sum-of-squares: one wave per row of a [R][512] matrix ----
__global__ __launch_bounds__(256) void rowss_kernel(const float* __restrict__ src,
                                                    float* __restrict__ dst) {
  int row  = (blockIdx.x * 256 + threadIdx.x) >> 6;
  int lane = threadIdx.x & 63;
  const float* p = src + (size_t)row * D_DIM;
  float4 a = *(const float4*)&p[lane * 4];
  float4 b = *(const float4*)&p[256 + lane * 4];
  float s = a.x*a.x + a.y*a.y + a.z*a.z + a.w*a.w
          + b.x*b.x + b.y*b.y + b.z*b.z + b.w*b.w;
#pragma unroll
  for (int off = 32; off > 0; off >>= 1) s += __shfl_down(s, off, 64);
  if (lane == 0) dst[row] = s;
}

// ---- fused distance + argmin, split-K ----
// grid (N/BN, SPLITK), block 256. Each block: 64 rows x 1024 codes.
__global__ __launch_bounds__(256) void vq_dist_kernel(
    const float* __restrict__ z, const float* __restrict__ W,
    const float* __restrict__ zz, const float* __restrict__ ww,
    float* __restrict__ bestd_out, int* __restrict__ besti_out) {
  __shared__ float zs[BD][68];   // [d][row], stride 68 (16B-aligned float4, low conflicts)
  __shared__ float ws_[BD][68];  // [d][code]
  __shared__ float rd[BN][16];
  __shared__ int   ri[BN][16];

  const int tid = threadIdx.x;
  const int tx = tid & 15;        // code group
  const int ty = tid >> 4;        // row group
  const int r0 = blockIdx.x * BN;
  const int kbase0 = blockIdx.y * KSPL;

  const int lr = tid >> 3;        // staging row 0..31
  const int lc = tid & 7;         // staging float4 col 0..7

  float bd[4];
  int   bi[4];
#pragma unroll
  for (int i = 0; i < 4; i++) { bd[i] = 3.4e38f; bi[i] = 0x7fffffff; }

  float zzr[4];
#pragma unroll
  for (int i = 0; i < 4; i++) zzr[i] = zz[r0 + ty * 4 + i];

  for (int kt = 0; kt < KSPL; kt += BK) {
    const int kb = kbase0 + kt;
    float c[4][4];
#pragma unroll
    for (int i = 0; i < 4; i++)
#pragma unroll
      for (int j = 0; j < 4; j++) c[i][j] = 0.f;

    for (int dt = 0; dt < D_DIM; dt += BD) {
      // stage z[r0..r0+63][dt..dt+31] transposed, W[kb..kb+63][dt..dt+31] transposed
#pragma unroll
      for (int h = 0; h < 2; h++) {
        const int r = lr + h * 32;
        const float4 v = *(const float4*)&z[(size_t)(r0 + r) * D_DIM + dt + lc * 4];
        zs[lc*4+0][r] = v.x; zs[lc*4+1][r] = v.y; zs[lc*4+2][r] = v.z; zs[lc*4+3][r] = v.w;
        const float4 u = *(const float4*)&W[(size_t)(kb + r) * D_DIM + dt + lc * 4];
        ws_[lc*4+0][r] = u.x; ws_[lc*4+1][r] = u.y; ws_[lc*4+2][r] = u.z; ws_[lc*4+3][r] = u.w;
      }
      __syncthreads();
#pragma unroll
      for (int d = 0; d < BD; d++) {
        const float4 a = *(const float4*)&zs[d][ty * 4];
        const float4 b = *(const float4*)&ws_[d][tx * 4];
        c[0][0] += a.x*b.x; c[0][1] += a.x*b.y; c[0][2] += a.x*b.z; c[0][3] += a.x*b.w;
        c[1][0] += a.y*b.x; c[1][1] += a.y*b.y; c[1][2] += a.y*b.z; c[1][3] += a.y*b.w;
        c[2][0] += a.z*b.x; c[2][1] += a.z*b.y; c[2][2] += a.z*b.z; c[2][3] += a.z*b.w;
        c[3][0] += a.w*b.x; c[3][1] += a.w*b.y; c[3][2] += a.w*b.z; c[3][3] += a.w*b.w;
      }
      __syncthreads();
    }
    // epilogue: distances + running argmin (k ascending => strict < keeps first min)
#pragma unroll
    for (int i = 0; i < 4; i++) {
#pragma unroll
      for (int j = 0; j < 4; j++) {
        const int col = kb + tx * 4 + j;
        // replicate reference rounding: (zz - 2*dot) + ww  (2*dot is exact)
        const float dist = (zzr[i] - 2.0f * c[i][j]) + ww[col];
        if (dist < bd[i]) { bd[i] = dist; bi[i] = col; }
      }
    }
  }

  // cross-thread reduce over the 16 tx threads sharing each row
#pragma unroll
  for (int i = 0; i < 4; i++) { rd[ty * 4 + i][tx] = bd[i]; ri[ty * 4 + i][tx] = bi[i]; }
  __syncthreads();
  if (tid < BN) {
    float best = rd[tid][0];
    int bidx = ri[tid][0];
#pragma unroll
    for (int t = 1; t < 16; t++) {
      const float dv = rd[tid][t];
      const int iv = ri[tid][t];
      if (dv < best || (dv == best && iv < bidx)) { best = dv; bidx = iv; }
    }
    bestd_out[(size_t)blockIdx.y * N_ROWS + r0 + tid] = best;
    besti_out[(size_t)blockIdx.y * N_ROWS + r0 + tid] = bidx;
  }
}

// ---- gather + straight-through + loss + counts: one wave per row ----
__global__ __launch_bounds__(256) void vq_gather_kernel(
    const float* __restrict__ z, const float* __restrict__ W,
    const float* __restrict__ bestd, const int* __restrict__ besti,
    float* __restrict__ out, float* __restrict__ ws_f) {
  const int row  = (blockIdx.x * 256 + threadIdx.x) >> 6;
  const int lane = threadIdx.x & 63;

  int bidx = 0;
  if (lane == 0) {
    float best = bestd[row];
    bidx = besti[row];
#pragma unroll
    for (int s = 1; s < SPLITK; s++) {
      const float dv = bestd[(size_t)s * N_ROWS + row];
      const int iv = besti[(size_t)s * N_ROWS + row];
      if (dv < best || (dv == best && iv < bidx)) { best = dv; bidx = iv; }
    }
    out[(size_t)N_ROWS * D_DIM + row] = (float)bidx;  // indices output (as f32)
    atomicAdd(&ws_f[OFF_COUNTS + bidx], 1.0f);
  }
  bidx = __shfl(bidx, 0, 64);

  const float* zp = z + (size_t)row * D_DIM;
  const float* wp = W + (size_t)bidx * D_DIM;
  float* op = out + (size_t)row * D_DIM;
  float lsum = 0.f;
#pragma unroll
  for (int h = 0; h < 2; h++) {
    const int d = h * 256 + lane * 4;
    const float4 zv = *(const float4*)&zp[d];
    const float4 wv = *(const float4*)&wp[d];
    float4 q;
    // straight-through: q = z + (z_q - z), exact reference op order
    q.x = zv.x + (wv.x - zv.x);
    q.y = zv.y + (wv.y - zv.y);
    q.z = zv.z + (wv.z - zv.z);
    q.w = zv.w + (wv.w - zv.w);
    *(float4*)&op[d] = q;
    float dx;
    dx = zv.x - wv.x; lsum += dx * dx;
    dx = zv.y - wv.y; lsum += dx * dx;
    dx = zv.z - wv.z; lsum += dx * dx;
    dx = zv.w - wv.w; lsum += dx * dx;
  }
#pragma unroll
  for (int off = 32; off > 0; off >>= 1) lsum += __shfl_down(lsum, off, 64);
  if (lane == 0) atomicAdd(&ws_f[OFF_LOSS], lsum);
}

// ---- finalize: loss scalar + perplexity ----
__global__ __launch_bounds__(256) void vq_finalize_kernel(const float* __restrict__ ws_f,
                                                          float* __restrict__ out) {
  const int tid = threadIdx.x;
  float s = 0.f;
  for (int k = tid; k < K_CODES; k += 256) {
    const float p = ws_f[OFF_COUNTS + k] * (1.0f / 8192.0f);
    s += p * logf(p + 1e-10f);
  }
#pragma unroll
  for (int off = 32; off > 0; off >>= 1) s += __shfl_down(s, off, 64);
  __shared__ float red[4];
  if ((tid & 63) == 0) red[tid >> 6] = s;
  __syncthreads();
  if (tid == 0) {
    const float tot = red[0] + red[1] + red[2] + red[3];
    out[(size_t)N_ROWS * D_DIM + N_ROWS]     = COMMIT * (ws_f[OFF_LOSS] / 4194304.0f);
    out[(size_t)N_ROWS * D_DIM + N_ROWS + 1] = expf(-tot);
  }
}

extern "C" void kernel_launch(void* const* d_in, const int* in_sizes, int n_in,
                              void* d_out, int out_size, void* d_ws, size_t ws_size,
                              hipStream_t stream) {
  const float* z = (const float*)d_in[0];
  const float* W = (const float*)d_in[1];
  float* out = (float*)d_out;
  float* ws_f = (float*)d_ws;
  int* ws_i = (int*)d_ws;

  // zero loss accumulator + counts
  hipMemsetAsync(d_ws, 0, (OFF_COUNTS + K_CODES) * sizeof(float), stream);

  // row norms
  rowss_kernel<<<N_ROWS / 4, 256, 0, stream>>>(z, ws_f + OFF_ZZ);
  rowss_kernel<<<K_CODES / 4, 256, 0, stream>>>(W, ws_f + OFF_WW);

  // distances + per-split argmin
  dim3 grid(N_ROWS / BN, SPLITK);
  vq_dist_kernel<<<grid, 256, 0, stream>>>(z, W, ws_f + OFF_ZZ, ws_f + OFF_WW,
                                           ws_f + OFF_BESTD, ws_i + OFF_BESTI);

  // gather + outputs + loss/counts
  vq_gather_kernel<<<N_ROWS / 4, 256, 0, stream>>>(z, W, ws_f + OFF_BESTD,
                                                   ws_i + OFF_BESTI, out, ws_f);

  // scalars
  vq_finalize_kernel<<<1, 256, 0, stream>>>(ws_f, out);
}

// Round 2
// 519.683 us; speedup vs baseline: 2.2516x; 2.2516x over previous
//
#include <hip/hip_runtime.h>
#include <math.h>

// VQ-VAE eval forward: z [4,2048,512] f32, W [8192,512] f32.
// Outputs (flat f32): quantized [4194304], indices [8192], loss [1], perplexity [1].
//
// Fast path: split-f16 3-pass MFMA distance GEMM (needs ~36 MB workspace).
// Fallback: round-1 fp32 VALU kernel (correctness-proven).

typedef __attribute__((ext_vector_type(8))) _Float16 f16x8;
typedef __attribute__((ext_vector_type(16))) float f32x16;

constexpr int N_ROWS = 8192;   // 4*2048
constexpr int K_CODES = 8192;
constexpr int D_DIM = 512;
constexpr float COMMIT = 0.25f;

// ---- workspace layout (float offsets) ----
constexpr size_t OFF_LOSS   = 0;
constexpr size_t OFF_COUNTS = 64;          // 8192 floats
constexpr size_t OFF_ZZ     = 16384;       // 8192 floats
constexpr size_t OFF_WW     = 24576;       // 8192 floats
constexpr size_t OFF_BESTD  = 32768;       // fast: [8192 rows][64 cb]; fallback: [8][8192]
constexpr size_t OFF_BESTI  = 557056;      // ints, same shapes
constexpr size_t F16_BASE_BYTES = 4325376; // = (557056 + 524288) * 4
constexpr size_t SPLIT_ELEMS = (size_t)8192 * 512;       // 4194304
constexpr size_t SPLIT_BYTES = SPLIT_ELEMS * 2;          // 8388608
constexpr size_t WS_NEED = F16_BASE_BYTES + 4 * SPLIT_BYTES; // 37,879,808 B

// fallback split-K
constexpr int SPLITK = 8;
constexpr int KSPL = K_CODES / SPLITK;

#define MFMA16(a, b, c) __builtin_amdgcn_mfma_f32_32x32x16_f16((a), (b), (c), 0, 0, 0)

__device__ __forceinline__ void gll16(const void* g, void* l) {
  __builtin_amdgcn_global_load_lds((const __attribute__((address_space(1))) void*)g,
                                   (__attribute__((address_space(3))) void*)l, 16, 0, 0);
}

// ---- row sum-of-squares: one wave per row of a [R][512] matrix ----
__global__ __launch_bounds__(256) void rowss_kernel(const float* __restrict__ src,
                                                    float* __restrict__ dst) {
  int row  = (blockIdx.x * 256 + threadIdx.x) >> 6;
  int lane = threadIdx.x & 63;
  const float* p = src + (size_t)row * D_DIM;
  float4 a = *(const float4*)&p[lane * 4];
  float4 b = *(const float4*)&p[256 + lane * 4];
  float s = a.x*a.x + a.y*a.y + a.z*a.z + a.w*a.w
          + b.x*b.x + b.y*b.y + b.z*b.z + b.w*b.w;
#pragma unroll
  for (int off = 32; off > 0; off >>= 1) s += __shfl_down(s, off, 64);
  if (lane == 0) dst[row] = s;
}

// ---- prepass: Dekker-split f32 -> (hi, lo*2048) f16, tiled [tile][chunk4][row128][8] ----
// grid (16 dt, 64 rowblk), block 256. Thread t: row = t>>1, d-half = (t&1)*16.
__global__ __launch_bounds__(256) void split_f16_kernel(const float* __restrict__ src,
                                                        unsigned short* __restrict__ hi,
                                                        unsigned short* __restrict__ lo,
                                                        float scale) {
  const int dt = blockIdx.x;
  const int rb = blockIdx.y;
  const int t = threadIdx.x;
  const int row = t >> 1;
  const int dh = (t & 1) * 16;
  const float* sp = src + ((size_t)(rb * 128 + row)) * D_DIM + dt * 32 + dh;
  const float4* sp4 = (const float4*)sp;
  float4 va = sp4[0], vb = sp4[1], vc = sp4[2], vd = sp4[3];
  float v[16] = {va.x, va.y, va.z, va.w, vb.x, vb.y, vb.z, vb.w,
                 vc.x, vc.y, vc.z, vc.w, vd.x, vd.y, vd.z, vd.w};
  const size_t tile = (size_t)(rb * 16 + dt) * 4096;
#pragma unroll
  for (int c2 = 0; c2 < 2; c2++) {
    const int chunk = (t & 1) * 2 + c2;
    f16x8 hv, lv;
#pragma unroll
    for (int j = 0; j < 8; j++) {
      const float x = v[c2 * 8 + j] * scale;
      const _Float16 h = (_Float16)x;
      const float r = (x - (float)h) * 2048.0f;  // exact split; pre-scale avoids denormals
      hv[j] = h;
      lv[j] = (_Float16)r;
    }
    const size_t off = tile + (size_t)chunk * 1024 + (size_t)row * 8;
    *(f16x8*)(hi + off) = hv;
    *(f16x8*)(lo + off) = lv;
  }
}

// ---- fast path: 128x128 tile distance + argmin via 3-pass split-f16 MFMA ----
// grid (64 cb, 64 rb), 256 threads / 4 waves (2x2 of 64x64), 32x32x16 frags.
__global__ __launch_bounds__(256, 2) void vq_dist_mfma_kernel(
    const unsigned short* __restrict__ zh_s, const unsigned short* __restrict__ zl_s,
    const unsigned short* __restrict__ wh_s, const unsigned short* __restrict__ wl_s,
    const float* __restrict__ zz, const float* __restrict__ ww,
    float* __restrict__ bestd, int* __restrict__ besti) {
  __shared__ f16x8 smem[2048];  // 32 KB: zh[0,512) zl[512,1024) wh[1024,1536) wl[1536,2048) 16B-units
  const int tid = threadIdx.x;
  const int cb = blockIdx.x, rb = blockIdx.y;
  const int lane = tid & 63, wv = tid >> 6;
  const int wr = wv >> 1, wc = wv & 1;
  const int lrow = lane & 31, lhi = lane >> 5;

  f32x16 acc_h[2][2];
  f32x16 acc_l[2][2];
#pragma unroll
  for (int i = 0; i < 2; i++)
#pragma unroll
    for (int j = 0; j < 2; j++) {
#pragma unroll
      for (int e = 0; e < 16; e++) { acc_h[i][j][e] = 0.0f; acc_l[i][j][e] = 0.0f; }
    }

  const int lofs = lane * 16;
  for (int dt = 0; dt < 16; dt++) {
    const size_t ztile = (size_t)(rb * 16 + dt) * 8192;  // bytes
    const size_t wtile = (size_t)(cb * 16 + dt) * 8192;
    const char* s0 = (const char*)zh_s + ztile;
    const char* s1 = (const char*)zl_s + ztile;
    const char* s2 = (const char*)wh_s + wtile;
    const char* s3 = (const char*)wl_s + wtile;
    char* lb = (char*)smem;
#pragma unroll
    for (int c = 0; c < 2; c++) {
      const int seg = (c * 4 + wv) * 1024;  // wave-uniform LDS dest; HW adds lane*16
      gll16(s0 + seg + lofs, lb + seg);
      gll16(s1 + seg + lofs, lb + 8192 + seg);
      gll16(s2 + seg + lofs, lb + 16384 + seg);
      gll16(s3 + seg + lofs, lb + 24576 + seg);
    }
    __syncthreads();
#pragma unroll
    for (int ks = 0; ks < 2; ks++) {
      const int ch = ks * 2 + lhi;
      const int abase = ch * 128 + wr * 64 + lrow;
      const int bbase = ch * 128 + wc * 64 + lrow;
      f16x8 ah[2], al[2], bh[2], bl[2];
      ah[0] = smem[abase];        ah[1] = smem[abase + 32];
      al[0] = smem[512 + abase];  al[1] = smem[512 + abase + 32];
      bh[0] = smem[1024 + bbase]; bh[1] = smem[1024 + bbase + 32];
      bl[0] = smem[1536 + bbase]; bl[1] = smem[1536 + bbase + 32];
#pragma unroll
      for (int rf = 0; rf < 2; rf++)
#pragma unroll
        for (int cf = 0; cf < 2; cf++) {
          acc_h[rf][cf] = MFMA16(ah[rf], bh[cf], acc_h[rf][cf]);
          acc_l[rf][cf] = MFMA16(ah[rf], bl[cf], acc_l[rf][cf]);
          acc_l[rf][cf] = MFMA16(al[rf], bh[cf], acc_l[rf][cf]);
        }
    }
    __syncthreads();
  }

  // ---- epilogue: distances with reference rounding + lexicographic-first argmin ----
  float* rd = (float*)smem;                  // [128][2]
  int*   ri = (int*)((char*)smem + 1024);    // [128][2]
  const int c0 = cb * 128 + wc * 64 + lrow;
  const int c1 = c0 + 32;
  const float ww0 = ww[c0], ww1 = ww[c1];
#pragma unroll
  for (int rf = 0; rf < 2; rf++) {
#pragma unroll
    for (int reg = 0; reg < 16; reg++) {
      const int rloc = wr * 64 + rf * 32 + (reg & 3) + 8 * (reg >> 2) + 4 * lhi;
      const float zzr = zz[rb * 128 + rloc];
      // dot*2^13 = acc_h + acc_l*2^-11 ; 2*dot = that * 2^-12 (pow-2 exact)
      const float a0 = acc_h[rf][0][reg] + acc_l[rf][0][reg] * (1.0f / 2048.0f);
      const float a1 = acc_h[rf][1][reg] + acc_l[rf][1][reg] * (1.0f / 2048.0f);
      const float t0 = zzr - a0 * (1.0f / 4096.0f);
      const float t1 = zzr - a1 * (1.0f / 4096.0f);
      float d = t0 + ww0; int idx = c0;
      const float d1 = t1 + ww1;
      if (d1 < d) { d = d1; idx = c1; }
#pragma unroll
      for (int m = 1; m <= 16; m <<= 1) {  // reduce across the 32 lanes sharing this row
        const float od = __shfl_xor(d, m, 64);
        const int   oi = __shfl_xor(idx, m, 64);
        if (od < d || (od == d && oi < idx)) { d = od; idx = oi; }
      }
      if (lrow == 0) { rd[rloc * 2 + wc] = d; ri[rloc * 2 + wc] = idx; }
    }
  }
  __syncthreads();
  if (tid < 128) {
    float d0 = rd[tid * 2]; int i0 = ri[tid * 2];
    const float d1v = rd[tid * 2 + 1]; const int i1 = ri[tid * 2 + 1];
    if (d1v < d0 || (d1v == d0 && i1 < i0)) { d0 = d1v; i0 = i1; }
    bestd[(size_t)(rb * 128 + tid) * 64 + cb] = d0;
    besti[(size_t)(rb * 128 + tid) * 64 + cb] = i0;
  }
}

// ---- fast-path gather: 64 candidates/row, one wave per row ----
__global__ __launch_bounds__(256) void vq_gather64_kernel(
    const float* __restrict__ z, const float* __restrict__ W,
    const float* __restrict__ bestd, const int* __restrict__ besti,
    float* __restrict__ out, float* __restrict__ ws_f) {
  const int row  = (blockIdx.x * 256 + threadIdx.x) >> 6;
  const int lane = threadIdx.x & 63;
  float d = bestd[(size_t)row * 64 + lane];
  int idx = besti[(size_t)row * 64 + lane];
#pragma unroll
  for (int m = 1; m <= 32; m <<= 1) {
    const float od = __shfl_xor(d, m, 64);
    const int   oi = __shfl_xor(idx, m, 64);
    if (od < d || (od == d && oi < idx)) { d = od; idx = oi; }
  }
  const int bidx = idx;  // all 64 lanes agree
  if (lane == 0) {
    out[(size_t)N_ROWS * D_DIM + row] = (float)bidx;
    atomicAdd(&ws_f[OFF_COUNTS + bidx], 1.0f);
  }
  const float* zp = z + (size_t)row * D_DIM;
  const float* wp = W + (size_t)bidx * D_DIM;
  float* op = out + (size_t)row * D_DIM;
  float lsum = 0.f;
#pragma unroll
  for (int h = 0; h < 2; h++) {
    const int dd = h * 256 + lane * 4;
    const float4 zv = *(const float4*)&zp[dd];
    const float4 wv = *(const float4*)&wp[dd];
    float4 q;
    q.x = zv.x + (wv.x - zv.x);
    q.y = zv.y + (wv.y - zv.y);
    q.z = zv.z + (wv.z - zv.z);
    q.w = zv.w + (wv.w - zv.w);
    *(float4*)&op[dd] = q;
    float dx;
    dx = zv.x - wv.x; lsum += dx * dx;
    dx = zv.y - wv.y; lsum += dx * dx;
    dx = zv.z - wv.z; lsum += dx * dx;
    dx = zv.w - wv.w; lsum += dx * dx;
  }
#pragma unroll
  for (int off = 32; off > 0; off >>= 1) lsum += __shfl_down(lsum, off, 64);
  if (lane == 0) atomicAdd(&ws_f[OFF_LOSS], lsum);
}

// ================= fallback fp32 path (round-1, proven) =================
constexpr int BN = 64, BK = 64, BD = 32;
__global__ __launch_bounds__(256) void vq_dist_kernel(
    const float* __restrict__ z, const float* __restrict__ W,
    const float* __restrict__ zz, const float* __restrict__ ww,
    float* __restrict__ bestd_out, int* __restrict__ besti_out) {
  __shared__ float zs[BD][68];
  __shared__ float ws_[BD][68];
  __shared__ float rd[BN][16];
  __shared__ int   ri[BN][16];
  const int tid = threadIdx.x;
  const int tx = tid & 15;
  const int ty = tid >> 4;
  const int r0 = blockIdx.x * BN;
  const int kbase0 = blockIdx.y * KSPL;
  const int lr = tid >> 3;
  const int lc = tid & 7;
  float bd[4]; int bi[4];
#pragma unroll
  for (int i = 0; i < 4; i++) { bd[i] = 3.4e38f; bi[i] = 0x7fffffff; }
  float zzr[4];
#pragma unroll
  for (int i = 0; i < 4; i++) zzr[i] = zz[r0 + ty * 4 + i];
  for (int kt = 0; kt < KSPL; kt += BK) {
    const int kb = kbase0 + kt;
    float c[4][4];
#pragma unroll
    for (int i = 0; i < 4; i++)
#pragma unroll
      for (int j = 0; j < 4; j++) c[i][j] = 0.f;
    for (int dtt = 0; dtt < D_DIM; dtt += BD) {
#pragma unroll
      for (int h = 0; h < 2; h++) {
        const int r = lr + h * 32;
        const float4 v = *(const float4*)&z[(size_t)(r0 + r) * D_DIM + dtt + lc * 4];
        zs[lc*4+0][r] = v.x; zs[lc*4+1][r] = v.y; zs[lc*4+2][r] = v.z; zs[lc*4+3][r] = v.w;
        const float4 u = *(const float4*)&W[(size_t)(kb + r) * D_DIM + dtt + lc * 4];
        ws_[lc*4+0][r] = u.x; ws_[lc*4+1][r] = u.y; ws_[lc*4+2][r] = u.z; ws_[lc*4+3][r] = u.w;
      }
      __syncthreads();
#pragma unroll
      for (int d = 0; d < BD; d++) {
        const float4 a = *(const float4*)&zs[d][ty * 4];
        const float4 b = *(const float4*)&ws_[d][tx * 4];
        c[0][0] += a.x*b.x; c[0][1] += a.x*b.y; c[0][2] += a.x*b.z; c[0][3] += a.x*b.w;
        c[1][0] += a.y*b.x; c[1][1] += a.y*b.y; c[1][2] += a.y*b.z; c[1][3] += a.y*b.w;
        c[2][0] += a.z*b.x; c[2][1] += a.z*b.y; c[2][2] += a.z*b.z; c[2][3] += a.z*b.w;
        c[3][0] += a.w*b.x; c[3][1] += a.w*b.y; c[3][2] += a.w*b.z; c[3][3] += a.w*b.w;
      }
      __syncthreads();
    }
#pragma unroll
    for (int i = 0; i < 4; i++) {
#pragma unroll
      for (int j = 0; j < 4; j++) {
        const int col = kb + tx * 4 + j;
        const float dist = (zzr[i] - 2.0f * c[i][j]) + ww[col];
        if (dist < bd[i]) { bd[i] = dist; bi[i] = col; }
      }
    }
  }
#pragma unroll
  for (int i = 0; i < 4; i++) { rd[ty * 4 + i][tx] = bd[i]; ri[ty * 4 + i][tx] = bi[i]; }
  __syncthreads();
  if (tid < BN) {
    float best = rd[tid][0]; int bidx = ri[tid][0];
#pragma unroll
    for (int t = 1; t < 16; t++) {
      const float dv = rd[tid][t]; const int iv = ri[tid][t];
      if (dv < best || (dv == best && iv < bidx)) { best = dv; bidx = iv; }
    }
    bestd_out[(size_t)blockIdx.y * N_ROWS + r0 + tid] = best;
    besti_out[(size_t)blockIdx.y * N_ROWS + r0 + tid] = bidx;
  }
}

__global__ __launch_bounds__(256) void vq_gather8_kernel(
    const float* __restrict__ z, const float* __restrict__ W,
    const float* __restrict__ bestd, const int* __restrict__ besti,
    float* __restrict__ out, float* __restrict__ ws_f) {
  const int row  = (blockIdx.x * 256 + threadIdx.x) >> 6;
  const int lane = threadIdx.x & 63;
  int bidx = 0;
  if (lane == 0) {
    float best = bestd[row];
    bidx = besti[row];
#pragma unroll
    for (int s = 1; s < SPLITK; s++) {
      const float dv = bestd[(size_t)s * N_ROWS + row];
      const int iv = besti[(size_t)s * N_ROWS + row];
      if (dv < best || (dv == best && iv < bidx)) { best = dv; bidx = iv; }
    }
    out[(size_t)N_ROWS * D_DIM + row] = (float)bidx;
    atomicAdd(&ws_f[OFF_COUNTS + bidx], 1.0f);
  }
  bidx = __shfl(bidx, 0, 64);
  const float* zp = z + (size_t)row * D_DIM;
  const float* wp = W + (size_t)bidx * D_DIM;
  float* op = out + (size_t)row * D_DIM;
  float lsum = 0.f;
#pragma unroll
  for (int h = 0; h < 2; h++) {
    const int d = h * 256 + lane * 4;
    const float4 zv = *(const float4*)&zp[d];
    const float4 wv = *(const float4*)&wp[d];
    float4 q;
    q.x = zv.x + (wv.x - zv.x);
    q.y = zv.y + (wv.y - zv.y);
    q.z = zv.z + (wv.z - zv.z);
    q.w = zv.w + (wv.w - zv.w);
    *(float4*)&op[d] = q;
    float dx;
    dx = zv.x - wv.x; lsum += dx * dx;
    dx = zv.y - wv.y; lsum += dx * dx;
    dx = zv.z - wv.z; lsum += dx * dx;
    dx = zv.w - wv.w; lsum += dx * dx;
  }
#pragma unroll
  for (int off = 32; off > 0; off >>= 1) lsum += __shfl_down(lsum, off, 64);
  if (lane == 0) atomicAdd(&ws_f[OFF_LOSS], lsum);
}

// ---- finalize: loss scalar + perplexity ----
__global__ __launch_bounds__(256) void vq_finalize_kernel(const float* __restrict__ ws_f,
                                                          float* __restrict__ out) {
  const int tid = threadIdx.x;
  float s = 0.f;
  for (int k = tid; k < K_CODES; k += 256) {
    const float p = ws_f[OFF_COUNTS + k] * (1.0f / 8192.0f);
    s += p * logf(p + 1e-10f);
  }
#pragma unroll
  for (int off = 32; off > 0; off >>= 1) s += __shfl_down(s, off, 64);
  __shared__ float red[4];
  if ((tid & 63) == 0) red[tid >> 6] = s;
  __syncthreads();
  if (tid == 0) {
    const float tot = red[0] + red[1] + red[2] + red[3];
    out[(size_t)N_ROWS * D_DIM + N_ROWS]     = COMMIT * (ws_f[OFF_LOSS] / 4194304.0f);
    out[(size_t)N_ROWS * D_DIM + N_ROWS + 1] = expf(-tot);
  }
}

extern "C" void kernel_launch(void* const* d_in, const int* in_sizes, int n_in,
                              void* d_out, int out_size, void* d_ws, size_t ws_size,
                              hipStream_t stream) {
  const float* z = (const float*)d_in[0];
  const float* W = (const float*)d_in[1];
  float* out = (float*)d_out;
  float* ws_f = (float*)d_ws;
  int* ws_i = (int*)d_ws;

  hipMemsetAsync(d_ws, 0, (OFF_COUNTS + K_CODES) * sizeof(float), stream);

  rowss_kernel<<<N_ROWS / 4, 256, 0, stream>>>(z, ws_f + OFF_ZZ);
  rowss_kernel<<<K_CODES / 4, 256, 0, stream>>>(W, ws_f + OFF_WW);

  if (ws_size >= WS_NEED) {
    unsigned short* zh = (unsigned short*)((char*)d_ws + F16_BASE_BYTES);
    unsigned short* zl = zh + SPLIT_ELEMS;
    unsigned short* wh = zl + SPLIT_ELEMS;
    unsigned short* wl = wh + SPLIT_ELEMS;
    split_f16_kernel<<<dim3(16, 64), 256, 0, stream>>>(z, zh, zl, 1.0f);
    split_f16_kernel<<<dim3(16, 64), 256, 0, stream>>>(W, wh, wl, 8192.0f);
    vq_dist_mfma_kernel<<<dim3(64, 64), 256, 0, stream>>>(
        zh, zl, wh, wl, ws_f + OFF_ZZ, ws_f + OFF_WW,
        ws_f + OFF_BESTD, ws_i + OFF_BESTI);
    vq_gather64_kernel<<<N_ROWS / 4, 256, 0, stream>>>(
        z, W, ws_f + OFF_BESTD, ws_i + OFF_BESTI, out, ws_f);
  } else {
    dim3 grid(N_ROWS / BN, SPLITK);
    vq_dist_kernel<<<grid, 256, 0, stream>>>(z, W, ws_f + OFF_ZZ, ws_f + OFF_WW,
                                             ws_f + OFF_BESTD, ws_i + OFF_BESTI);
    vq_gather8_kernel<<<N_ROWS / 4, 256, 0, stream>>>(z, W, ws_f + OFF_BESTD,
                                                      ws_i + OFF_BESTI, out, ws_f);
  }

  vq_finalize_kernel<<<1, 256, 0, stream>>>(ws_f, out);
}

// Round 4
// 418.165 us; speedup vs baseline: 2.7982x; 1.2428x over previous
//
#include <hip/hip_runtime.h>
#include <math.h>

// VQ-VAE eval forward: z [4,2048,512] f32, W [8192,512] f32.
// Outputs (flat f32): quantized [4194304], indices [8192], loss [1], perplexity [1].
//
// Fast path: split-f16 3-pass MFMA distance GEMM, z-frags from global (L1/L2),
// W-frags via double-buffered LDS with counted-vmcnt 2-phase prefetch.
// Fallback: round-1 fp32 VALU kernel (correctness-proven).

typedef __attribute__((ext_vector_type(8))) _Float16 f16x8;
typedef __attribute__((ext_vector_type(16))) float f32x16;

constexpr int N_ROWS = 8192;   // 4*2048
constexpr int K_CODES = 8192;
constexpr int D_DIM = 512;
constexpr float COMMIT = 0.25f;

// ---- workspace layout (float offsets) ----
constexpr size_t OFF_LOSS    = 0;
constexpr size_t OFF_COUNTS  = 64;         // 8192 floats
constexpr size_t OFF_PARTIAL = 8256;       // 2048 floats (per-block loss partials)
constexpr size_t OFF_ZZ      = 16384;      // 8192 floats
constexpr size_t OFF_WW      = 24576;      // 8192 floats
constexpr size_t OFF_BESTD   = 32768;      // fast: [8192 rows][64 cb]; fallback: [8][8192]
constexpr size_t OFF_BESTI   = 557056;     // ints, same shapes
constexpr size_t F16_BASE_BYTES = 4325376; // = (557056 + 524288) * 4
constexpr size_t SPLIT_ELEMS = (size_t)8192 * 512;
constexpr size_t SPLIT_BYTES = SPLIT_ELEMS * 2;
constexpr size_t WS_NEED = F16_BASE_BYTES + 4 * SPLIT_BYTES;

constexpr int SPLITK = 8;
constexpr int KSPL = K_CODES / SPLITK;

#define MFMA16(a, b, c) __builtin_amdgcn_mfma_f32_32x32x16_f16((a), (b), (c), 0, 0, 0)

__device__ __forceinline__ void gll16(const void* g, void* l) {
  __builtin_amdgcn_global_load_lds((const __attribute__((address_space(1))) void*)g,
                                   (__attribute__((address_space(3))) void*)l, 16, 0, 0);
}

// ---- row sum-of-squares: one wave per row of a [R][512] matrix ----
__global__ __launch_bounds__(256) void rowss_kernel(const float* __restrict__ src,
                                                    float* __restrict__ dst) {
  int row  = (blockIdx.x * 256 + threadIdx.x) >> 6;
  int lane = threadIdx.x & 63;
  const float* p = src + (size_t)row * D_DIM;
  float4 a = *(const float4*)&p[lane * 4];
  float4 b = *(const float4*)&p[256 + lane * 4];
  float s = a.x*a.x + a.y*a.y + a.z*a.z + a.w*a.w
          + b.x*b.x + b.y*b.y + b.z*b.z + b.w*b.w;
#pragma unroll
  for (int off = 32; off > 0; off >>= 1) s += __shfl_down(s, off, 64);
  if (lane == 0) dst[row] = s;
}

// ---- prepass: Dekker-split f32 -> (hi, lo*2048) f16, tiled [tile][chunk4][row128][8] ----
__global__ __launch_bounds__(256) void split_f16_kernel(const float* __restrict__ src,
                                                        unsigned short* __restrict__ hi,
                                                        unsigned short* __restrict__ lo,
                                                        float scale) {
  const int dt = blockIdx.x;
  const int rb = blockIdx.y;
  const int t = threadIdx.x;
  const int row = t >> 1;
  const int dh = (t & 1) * 16;
  const float* sp = src + ((size_t)(rb * 128 + row)) * D_DIM + dt * 32 + dh;
  const float4* sp4 = (const float4*)sp;
  float4 va = sp4[0], vb = sp4[1], vc = sp4[2], vd = sp4[3];
  float v[16] = {va.x, va.y, va.z, va.w, vb.x, vb.y, vb.z, vb.w,
                 vc.x, vc.y, vc.z, vc.w, vd.x, vd.y, vd.z, vd.w};
  const size_t tile = (size_t)(rb * 16 + dt) * 4096;
#pragma unroll
  for (int c2 = 0; c2 < 2; c2++) {
    const int chunk = (t & 1) * 2 + c2;
    f16x8 hv, lv;
#pragma unroll
    for (int j = 0; j < 8; j++) {
      const float x = v[c2 * 8 + j] * scale;
      const _Float16 h = (_Float16)x;
      const float r = (x - (float)h) * 2048.0f;  // exact split; pre-scale avoids denormals
      hv[j] = h;
      lv[j] = (_Float16)r;
    }
    const size_t off = tile + (size_t)chunk * 1024 + (size_t)row * 8;
    *(f16x8*)(hi + off) = hv;
    *(f16x8*)(lo + off) = lv;
  }
}

// ---- fast path: 128x128 tile distance + argmin, z from global, W via LDS dbuf ----
// grid (64 cb, 64 rb), 256 threads / 4 waves (2x2 of 64x64), 32x32x16 frags.
__global__ __launch_bounds__(256, 2) void vq_dist_mfma_kernel(
    const unsigned short* __restrict__ zh_s, const unsigned short* __restrict__ zl_s,
    const unsigned short* __restrict__ wh_s, const unsigned short* __restrict__ wl_s,
    const float* __restrict__ zz, const float* __restrict__ ww,
    float* __restrict__ bestd, int* __restrict__ besti) {
  __shared__ char smem[32768];  // 2 x 16KB W buffers: wh [0,8K), wl [8K,16K) per buffer
  const int tid = threadIdx.x;
  const int cb = blockIdx.x, rb = blockIdx.y;
  const int lane = tid & 63, wv = tid >> 6;
  const int wr = wv >> 1, wc = wv & 1;
  const int lrow = lane & 31, lhi = lane >> 5;
  const int lofs = lane * 16;

  f32x16 acc_h[2][2], acc_l[2][2];
#pragma unroll
  for (int i = 0; i < 2; i++)
#pragma unroll
    for (int j = 0; j < 2; j++)
#pragma unroll
      for (int e = 0; e < 16; e++) { acc_h[i][j][e] = 0.0f; acc_l[i][j][e] = 0.0f; }

  const f16x8* zh8 = (const f16x8*)zh_s;
  const f16x8* zl8 = (const f16x8*)zl_s;

  // stage W tile dt into LDS buffer buf (4 gll16 per thread-wave set, 16KB total)
  auto STAGE = [&](int buf, int dt) {
    const size_t wt = ((size_t)(cb * 16 + dt)) * 8192;
    const char* sh = (const char*)wh_s + wt;
    const char* sl = (const char*)wl_s + wt;
    char* lb = smem + buf * 16384;
#pragma unroll
    for (int c = 0; c < 2; c++) {
      const int seg = (c * 4 + wv) * 1024;  // wave-uniform LDS dest; HW adds lane*16
      gll16(sh + seg + lofs, lb + seg);
      gll16(sl + seg + lofs, lb + 8192 + seg);
    }
  };

  f16x8 zAh[2][2], zAl[2][2], zBh[2][2], zBl[2][2];  // [ks][rf]
  auto ZLOAD = [&](f16x8 (&h)[2][2], f16x8 (&l)[2][2], int dt) {
    const int tu = (rb * 16 + dt) * 512;
#pragma unroll
    for (int ks = 0; ks < 2; ks++) {
      const int zi = tu + (ks * 2 + lhi) * 128 + wr * 64 + lrow;
#pragma unroll
      for (int rf = 0; rf < 2; rf++) {
        h[ks][rf] = zh8[zi + rf * 32];
        l[ks][rf] = zl8[zi + rf * 32];
      }
    }
  };

  auto COMPUTE = [&](int buf, f16x8 (&h)[2][2], f16x8 (&l)[2][2]) {
    const f16x8* wb = (const f16x8*)(smem + buf * 16384);
#pragma unroll
    for (int ks = 0; ks < 2; ks++) {
      const int wu = (ks * 2 + lhi) * 128 + wc * 64 + lrow;
      f16x8 bh[2], bl[2];
#pragma unroll
      for (int cf = 0; cf < 2; cf++) {
        bh[cf] = wb[wu + cf * 32];
        bl[cf] = wb[512 + wu + cf * 32];
      }
      __builtin_amdgcn_s_setprio(1);
#pragma unroll
      for (int rf = 0; rf < 2; rf++)
#pragma unroll
        for (int cf = 0; cf < 2; cf++) {
          acc_h[rf][cf] = MFMA16(h[ks][rf], bh[cf], acc_h[rf][cf]);
          acc_l[rf][cf] = MFMA16(h[ks][rf], bl[cf], acc_l[rf][cf]);
          acc_l[rf][cf] = MFMA16(l[ks][rf], bh[cf], acc_l[rf][cf]);
        }
      __builtin_amdgcn_s_setprio(0);
    }
  };

  // prologue
  STAGE(0, 0);
  ZLOAD(zAh, zAl, 0);
  asm volatile("s_waitcnt vmcnt(8)" ::: "memory");  // drain the 4 gll16 (oldest)
  __builtin_amdgcn_s_barrier();

  for (int dtp = 0; dtp < 8; dtp++) {
    const int dt0 = dtp * 2;
    STAGE(1, dt0 + 1);
    ZLOAD(zBh, zBl, dt0 + 1);
    COMPUTE(0, zAh, zAl);
    asm volatile("s_waitcnt vmcnt(8)" ::: "memory");  // buf1 staged; 8 z-loads stay in flight
    __builtin_amdgcn_s_barrier();
    if (dtp < 7) {
      STAGE(0, dt0 + 2);
      ZLOAD(zAh, zAl, dt0 + 2);
    }
    COMPUTE(1, zBh, zBl);
    asm volatile("s_waitcnt vmcnt(8)" ::: "memory");
    __builtin_amdgcn_s_barrier();
  }

  // ---- epilogue: distances with reference rounding + lexicographic-first argmin ----
  float* rd = (float*)smem;                  // [128][2]
  int*   ri = (int*)(smem + 1024);           // [128][2]
  const int c0 = cb * 128 + wc * 64 + lrow;
  const int c1 = c0 + 32;
  const float ww0 = ww[c0], ww1 = ww[c1];
#pragma unroll
  for (int rf = 0; rf < 2; rf++) {
#pragma unroll
    for (int reg = 0; reg < 16; reg++) {
      const int rloc = wr * 64 + rf * 32 + (reg & 3) + 8 * (reg >> 2) + 4 * lhi;
      const float zzr = zz[rb * 128 + rloc];
      // dot*2^13 = acc_h + acc_l*2^-11 ; 2*dot = that * 2^-12 (pow-2 exact)
      const float a0 = acc_h[rf][0][reg] + acc_l[rf][0][reg] * (1.0f / 2048.0f);
      const float a1 = acc_h[rf][1][reg] + acc_l[rf][1][reg] * (1.0f / 2048.0f);
      const float t0 = zzr - a0 * (1.0f / 4096.0f);
      const float t1 = zzr - a1 * (1.0f / 4096.0f);
      float d = t0 + ww0; int idx = c0;
      const float d1 = t1 + ww1;
      if (d1 < d) { d = d1; idx = c1; }
#pragma unroll
      for (int m = 1; m <= 16; m <<= 1) {  // reduce across 32 lanes sharing this row
        const float od = __shfl_xor(d, m, 64);
        const int   oi = __shfl_xor(idx, m, 64);
        if (od < d || (od == d && oi < idx)) { d = od; idx = oi; }
      }
      if (lrow == 0) { rd[rloc * 2 + wc] = d; ri[rloc * 2 + wc] = idx; }
    }
  }
  __syncthreads();
  if (tid < 128) {
    float d0 = rd[tid * 2]; int i0 = ri[tid * 2];
    const float d1v = rd[tid * 2 + 1]; const int i1 = ri[tid * 2 + 1];
    if (d1v < d0 || (d1v == d0 && i1 < i0)) { d0 = d1v; i0 = i1; }
    bestd[(size_t)(rb * 128 + tid) * 64 + cb] = d0;
    besti[(size_t)(rb * 128 + tid) * 64 + cb] = i0;
  }
}

// ---- fast-path gather: 64 candidates/row, one wave per row; loss via block partials ----
__global__ __launch_bounds__(256) void vq_gather64_kernel(
    const float* __restrict__ z, const float* __restrict__ W,
    const float* __restrict__ bestd, const int* __restrict__ besti,
    float* __restrict__ out, float* __restrict__ ws_f) {
  const int row  = (blockIdx.x * 256 + threadIdx.x) >> 6;
  const int lane = threadIdx.x & 63;
  float d = bestd[(size_t)row * 64 + lane];
  int idx = besti[(size_t)row * 64 + lane];
#pragma unroll
  for (int m = 1; m <= 32; m <<= 1) {
    const float od = __shfl_xor(d, m, 64);
    const int   oi = __shfl_xor(idx, m, 64);
    if (od < d || (od == d && oi < idx)) { d = od; idx = oi; }
  }
  const int bidx = idx;  // all 64 lanes agree
  if (lane == 0) {
    out[(size_t)N_ROWS * D_DIM + row] = (float)bidx;
    atomicAdd(&ws_f[OFF_COUNTS + bidx], 1.0f);  // integer-valued: order-independent
  }
  const float* zp = z + (size_t)row * D_DIM;
  const float* wp = W + (size_t)bidx * D_DIM;
  float* op = out + (size_t)row * D_DIM;
  float lsum = 0.f;
#pragma unroll
  for (int h = 0; h < 2; h++) {
    const int dd = h * 256 + lane * 4;
    const float4 zv = *(const float4*)&zp[dd];
    const float4 wv = *(const float4*)&wp[dd];
    float4 q;
    q.x = zv.x + (wv.x - zv.x);
    q.y = zv.y + (wv.y - zv.y);
    q.z = zv.z + (wv.z - zv.z);
    q.w = zv.w + (wv.w - zv.w);
    *(float4*)&op[dd] = q;
    float dx;
    dx = zv.x - wv.x; lsum += dx * dx;
    dx = zv.y - wv.y; lsum += dx * dx;
    dx = zv.z - wv.z; lsum += dx * dx;
    dx = zv.w - wv.w; lsum += dx * dx;
  }
#pragma unroll
  for (int off = 32; off > 0; off >>= 1) lsum += __shfl_down(lsum, off, 64);
  __shared__ float lred[4];
  if (lane == 0) lred[threadIdx.x >> 6] = lsum;
  __syncthreads();
  if (threadIdx.x == 0)
    ws_f[OFF_PARTIAL + blockIdx.x] = lred[0] + lred[1] + lred[2] + lred[3];
}

// ================= fallback fp32 path (round-1, proven) =================
constexpr int BN = 64, BK = 64, BD = 32;
__global__ __launch_bounds__(256) void vq_dist_kernel(
    const float* __restrict__ z, const float* __restrict__ W,
    const float* __restrict__ zz, const float* __restrict__ ww,
    float* __restrict__ bestd_out, int* __restrict__ besti_out) {
  __shared__ float zs[BD][68];
  __shared__ float ws_[BD][68];
  __shared__ float rd[BN][16];
  __shared__ int   ri[BN][16];
  const int tid = threadIdx.x;
  const int tx = tid & 15;
  const int ty = tid >> 4;
  const int r0 = blockIdx.x * BN;
  const int kbase0 = blockIdx.y * KSPL;
  const int lr = tid >> 3;
  const int lc = tid & 7;
  float bd[4]; int bi[4];
#pragma unroll
  for (int i = 0; i < 4; i++) { bd[i] = 3.4e38f; bi[i] = 0x7fffffff; }
  float zzr[4];
#pragma unroll
  for (int i = 0; i < 4; i++) zzr[i] = zz[r0 + ty * 4 + i];
  for (int kt = 0; kt < KSPL; kt += BK) {
    const int kb = kbase0 + kt;
    float c[4][4];
#pragma unroll
    for (int i = 0; i < 4; i++)
#pragma unroll
      for (int j = 0; j < 4; j++) c[i][j] = 0.f;
    for (int dtt = 0; dtt < D_DIM; dtt += BD) {
#pragma unroll
      for (int h = 0; h < 2; h++) {
        const int r = lr + h * 32;
        const float4 v = *(const float4*)&z[(size_t)(r0 + r) * D_DIM + dtt + lc * 4];
        zs[lc*4+0][r] = v.x; zs[lc*4+1][r] = v.y; zs[lc*4+2][r] = v.z; zs[lc*4+3][r] = v.w;
        const float4 u = *(const float4*)&W[(size_t)(kb + r) * D_DIM + dtt + lc * 4];
        ws_[lc*4+0][r] = u.x; ws_[lc*4+1][r] = u.y; ws_[lc*4+2][r] = u.z; ws_[lc*4+3][r] = u.w;
      }
      __syncthreads();
#pragma unroll
      for (int d = 0; d < BD; d++) {
        const float4 a = *(const float4*)&zs[d][ty * 4];
        const float4 b = *(const float4*)&ws_[d][tx * 4];
        c[0][0] += a.x*b.x; c[0][1] += a.x*b.y; c[0][2] += a.x*b.z; c[0][3] += a.x*b.w;
        c[1][0] += a.y*b.x; c[1][1] += a.y*b.y; c[1][2] += a.y*b.z; c[1][3] += a.y*b.w;
        c[2][0] += a.z*b.x; c[2][1] += a.z*b.y; c[2][2] += a.z*b.z; c[2][3] += a.z*b.w;
        c[3][0] += a.w*b.x; c[3][1] += a.w*b.y; c[3][2] += a.w*b.z; c[3][3] += a.w*b.w;
      }
      __syncthreads();
    }
#pragma unroll
    for (int i = 0; i < 4; i++) {
#pragma unroll
      for (int j = 0; j < 4; j++) {
        const int col = kb + tx * 4 + j;
        const float dist = (zzr[i] - 2.0f * c[i][j]) + ww[col];
        if (dist < bd[i]) { bd[i] = dist; bi[i] = col; }
      }
    }
  }
#pragma unroll
  for (int i = 0; i < 4; i++) { rd[ty * 4 + i][tx] = bd[i]; ri[ty * 4 + i][tx] = bi[i]; }
  __syncthreads();
  if (tid < BN) {
    float best = rd[tid][0]; int bidx = ri[tid][0];
#pragma unroll
    for (int t = 1; t < 16; t++) {
      const float dv = rd[tid][t]; const int iv = ri[tid][t];
      if (dv < best || (dv == best && iv < bidx)) { best = dv; bidx = iv; }
    }
    bestd_out[(size_t)blockIdx.y * N_ROWS + r0 + tid] = best;
    besti_out[(size_t)blockIdx.y * N_ROWS + r0 + tid] = bidx;
  }
}

__global__ __launch_bounds__(256) void vq_gather8_kernel(
    const float* __restrict__ z, const float* __restrict__ W,
    const float* __restrict__ bestd, const int* __restrict__ besti,
    float* __restrict__ out, float* __restrict__ ws_f) {
  const int row  = (blockIdx.x * 256 + threadIdx.x) >> 6;
  const int lane = threadIdx.x & 63;
  int bidx = 0;
  if (lane == 0) {
    float best = bestd[row];
    bidx = besti[row];
#pragma unroll
    for (int s = 1; s < SPLITK; s++) {
      const float dv = bestd[(size_t)s * N_ROWS + row];
      const int iv = besti[(size_t)s * N_ROWS + row];
      if (dv < best || (dv == best && iv < bidx)) { best = dv; bidx = iv; }
    }
    out[(size_t)N_ROWS * D_DIM + row] = (float)bidx;
    atomicAdd(&ws_f[OFF_COUNTS + bidx], 1.0f);
  }
  bidx = __shfl(bidx, 0, 64);
  const float* zp = z + (size_t)row * D_DIM;
  const float* wp = W + (size_t)bidx * D_DIM;
  float* op = out + (size_t)row * D_DIM;
  float lsum = 0.f;
#pragma unroll
  for (int h = 0; h < 2; h++) {
    const int d = h * 256 + lane * 4;
    const float4 zv = *(const float4*)&zp[d];
    const float4 wv = *(const float4*)&wp[d];
    float4 q;
    q.x = zv.x + (wv.x - zv.x);
    q.y = zv.y + (wv.y - zv.y);
    q.z = zv.z + (wv.z - zv.z);
    q.w = zv.w + (wv.w - zv.w);
    *(float4*)&op[d] = q;
    float dx;
    dx = zv.x - wv.x; lsum += dx * dx;
    dx = zv.y - wv.y; lsum += dx * dx;
    dx = zv.z - wv.z; lsum += dx * dx;
    dx = zv.w - wv.w; lsum += dx * dx;
  }
#pragma unroll
  for (int off = 32; off > 0; off >>= 1) lsum += __shfl_down(lsum, off, 64);
  if (lane == 0) atomicAdd(&ws_f[OFF_LOSS], lsum);
}

// ---- finalize: loss scalar + perplexity ----
__global__ __launch_bounds__(256) void vq_finalize_kernel(const float* __restrict__ ws_f,
                                                          float* __restrict__ out,
                                                          int use_partial) {
  const int tid = threadIdx.x;
  float ls = 0.f;
  if (use_partial) {
    for (int i = tid; i < 2048; i += 256) ls += ws_f[OFF_PARTIAL + i];
  }
  float s = 0.f;
  for (int k = tid; k < K_CODES; k += 256) {
    const float p = ws_f[OFF_COUNTS + k] * (1.0f / 8192.0f);
    s += p * logf(p + 1e-10f);
  }
#pragma unroll
  for (int off = 32; off > 0; off >>= 1) {
    s  += __shfl_down(s, off, 64);
    ls += __shfl_down(ls, off, 64);
  }
  __shared__ float red[4], redl[4];
  if ((tid & 63) == 0) { red[tid >> 6] = s; redl[tid >> 6] = ls; }
  __syncthreads();
  if (tid == 0) {
    const float tot = red[0] + red[1] + red[2] + red[3];
    const float L = use_partial ? (redl[0] + redl[1] + redl[2] + redl[3])
                                : ws_f[OFF_LOSS];
    out[(size_t)N_ROWS * D_DIM + N_ROWS]     = COMMIT * (L / 4194304.0f);
    out[(size_t)N_ROWS * D_DIM + N_ROWS + 1] = expf(-tot);
  }
}

extern "C" void kernel_launch(void* const* d_in, const int* in_sizes, int n_in,
                              void* d_out, int out_size, void* d_ws, size_t ws_size,
                              hipStream_t stream) {
  const float* z = (const float*)d_in[0];
  const float* W = (const float*)d_in[1];
  float* out = (float*)d_out;
  float* ws_f = (float*)d_ws;
  int* ws_i = (int*)d_ws;

  hipMemsetAsync(d_ws, 0, (OFF_COUNTS + K_CODES) * sizeof(float), stream);

  rowss_kernel<<<N_ROWS / 4, 256, 0, stream>>>(z, ws_f + OFF_ZZ);
  rowss_kernel<<<K_CODES / 4, 256, 0, stream>>>(W, ws_f + OFF_WW);

  if (ws_size >= WS_NEED) {
    unsigned short* zh = (unsigned short*)((char*)d_ws + F16_BASE_BYTES);
    unsigned short* zl = zh + SPLIT_ELEMS;
    unsigned short* wh = zl + SPLIT_ELEMS;
    unsigned short* wl = wh + SPLIT_ELEMS;
    split_f16_kernel<<<dim3(16, 64), 256, 0, stream>>>(z, zh, zl, 1.0f);
    split_f16_kernel<<<dim3(16, 64), 256, 0, stream>>>(W, wh, wl, 8192.0f);
    vq_dist_mfma_kernel<<<dim3(64, 64), 256, 0, stream>>>(
        zh, zl, wh, wl, ws_f + OFF_ZZ, ws_f + OFF_WW,
        ws_f + OFF_BESTD, ws_i + OFF_BESTI);
    vq_gather64_kernel<<<N_ROWS / 4, 256, 0, stream>>>(
        z, W, ws_f + OFF_BESTD, ws_i + OFF_BESTI, out, ws_f);
    vq_finalize_kernel<<<1, 256, 0, stream>>>(ws_f, out, 1);
  } else {
    dim3 grid(N_ROWS / BN, SPLITK);
    vq_dist_kernel<<<grid, 256, 0, stream>>>(z, W, ws_f + OFF_ZZ, ws_f + OFF_WW,
                                             ws_f + OFF_BESTD, ws_i + OFF_BESTI);
    vq_gather8_kernel<<<N_ROWS / 4, 256, 0, stream>>>(z, W, ws_f + OFF_BESTD,
                                                      ws_i + OFF_BESTI, out, ws_f);
    vq_finalize_kernel<<<1, 256, 0, stream>>>(ws_f, out, 0);
  }
}

// Round 5
// 310.574 us; speedup vs baseline: 3.7676x; 1.3464x over previous
//
#include <hip/hip_runtime.h>
#include <math.h>

// VQ-VAE eval forward: z [4,2048,512] f32, W [8192,512] f32.
// Outputs (flat f32): quantized [4194304], indices [8192], loss [1], perplexity [1].
//
// Fast path (two-stage):
//   1) screen: f16 hh-only MFMA GEMM -> top-2 approx candidates per (row, 64-code half)
//   2) rescore: exact fp32 reference-rounded distance for all candidates within EPS
//      of the row's approx min; fused with quantize/loss/counts outputs.
// Fallback: round-1 fp32 VALU kernel (correctness-proven).

typedef __attribute__((ext_vector_type(8))) _Float16 f16x8;
typedef __attribute__((ext_vector_type(16))) float f32x16;

constexpr int N_ROWS = 8192;   // 4*2048
constexpr int K_CODES = 8192;
constexpr int D_DIM = 512;
constexpr float COMMIT = 0.25f;
// screen-vs-reference pairwise offset bound ~1.9e-4 (f16 hh error 3.2e-5 + fl
// quantization 6.1e-5, pairwise x2); EPS = 3e-4 gives >1.5x margin while
// keeping expected survivors ~1.1/row.
constexpr float EPS = 3.0e-4f;

// ---- workspace layout (float offsets) ----
constexpr size_t OFF_LOSS    = 0;
constexpr size_t OFF_COUNTS  = 64;         // 8192 floats
constexpr size_t OFF_PARTIAL = 8256;       // 2048 floats (per-block loss partials)
constexpr size_t OFF_ZZ      = 16384;      // 8192 floats
constexpr size_t OFF_WW      = 24576;      // 8192 floats
constexpr size_t OFF_BESTD   = 32768;      // fast: [8192 rows][256]; fallback: [8][8192]
constexpr size_t OFF_BESTI   = 2129920;    // ints, same shapes
constexpr size_t F16_BASE_BYTES = 16908288; // = (2129920 + 2097152) * 4
constexpr size_t SPLIT_ELEMS = (size_t)8192 * 512;
constexpr size_t SPLIT_BYTES = SPLIT_ELEMS * 2;           // 8 MB each
constexpr size_t WS_NEED = F16_BASE_BYTES + 2 * SPLIT_BYTES; // 33,685,504 B

constexpr int SPLITK = 8;
constexpr int KSPL = K_CODES / SPLITK;

#define MFMA16(a, b, c) __builtin_amdgcn_mfma_f32_32x32x16_f16((a), (b), (c), 0, 0, 0)

__device__ __forceinline__ void gll16(const void* g, void* l) {
  __builtin_amdgcn_global_load_lds((const __attribute__((address_space(1))) void*)g,
                                   (__attribute__((address_space(3))) void*)l, 16, 0, 0);
}

__device__ __forceinline__ bool lexless(float da, int ia, float db, int ib) {
  return da < db || (da == db && ia < ib);
}

// ---- row sum-of-squares: one wave per row of a [R][512] matrix ----
__global__ __launch_bounds__(256) void rowss_kernel(const float* __restrict__ src,
                                                    float* __restrict__ dst) {
  int row  = (blockIdx.x * 256 + threadIdx.x) >> 6;
  int lane = threadIdx.x & 63;
  const float* p = src + (size_t)row * D_DIM;
  float4 a = *(const float4*)&p[lane * 4];
  float4 b = *(const float4*)&p[256 + lane * 4];
  float s = a.x*a.x + a.y*a.y + a.z*a.z + a.w*a.w
          + b.x*b.x + b.y*b.y + b.z*b.z + b.w*b.w;
#pragma unroll
  for (int off = 32; off > 0; off >>= 1) s += __shfl_down(s, off, 64);
  if (lane == 0) dst[row] = s;
}

// ---- prepass: f32 -> f16 hi part, tiled [tile][chunk4][row128][8] ----
__global__ __launch_bounds__(256) void split_hi_kernel(const float* __restrict__ src,
                                                       unsigned short* __restrict__ hi,
                                                       float scale) {
  const int dt = blockIdx.x;
  const int rb = blockIdx.y;
  const int t = threadIdx.x;
  const int row = t >> 1;
  const int dh = (t & 1) * 16;
  const float* sp = src + ((size_t)(rb * 128 + row)) * D_DIM + dt * 32 + dh;
  const float4* sp4 = (const float4*)sp;
  float4 va = sp4[0], vb = sp4[1], vc = sp4[2], vd = sp4[3];
  float v[16] = {va.x, va.y, va.z, va.w, vb.x, vb.y, vb.z, vb.w,
                 vc.x, vc.y, vc.z, vc.w, vd.x, vd.y, vd.z, vd.w};
  const size_t tile = (size_t)(rb * 16 + dt) * 4096;
#pragma unroll
  for (int c2 = 0; c2 < 2; c2++) {
    const int chunk = (t & 1) * 2 + c2;
    f16x8 hv;
#pragma unroll
    for (int j = 0; j < 8; j++) hv[j] = (_Float16)(v[c2 * 8 + j] * scale);
    *(f16x8*)(hi + tile + (size_t)chunk * 1024 + (size_t)row * 8) = hv;
  }
}

// ---- stage 1: screen. 128x128 tile, hh-only, top-2 per (row, 64-col half) ----
// grid (64 cb, 64 rb), block 256 (4 waves 2x2 of 64x64), 32x32x16 frags.
__global__ __launch_bounds__(256, 4) void vq_screen_kernel(
    const unsigned short* __restrict__ zh_s, const unsigned short* __restrict__ wh_s,
    const float* __restrict__ ww,
    float* __restrict__ bestd2, int* __restrict__ besti2) {
  __shared__ f16x8 smem[1024];  // zh [0,512), wh [512,1024) in f16x8 units (16 KB)
  const int tid = threadIdx.x;
  const int cb = blockIdx.x, rb = blockIdx.y;
  const int lane = tid & 63, wv = tid >> 6;
  const int wr = wv >> 1, wc = wv & 1;
  const int lrow = lane & 31, lhi = lane >> 5;
  const int lofs = lane * 16;

  f32x16 acc[2][2];
#pragma unroll
  for (int i = 0; i < 2; i++)
#pragma unroll
    for (int j = 0; j < 2; j++)
#pragma unroll
      for (int e = 0; e < 16; e++) acc[i][j][e] = 0.0f;

  for (int dt = 0; dt < 16; dt++) {
    __syncthreads();  // protect buffer from previous dt's readers
    const size_t zt = ((size_t)(rb * 16 + dt)) * 8192;
    const size_t wt = ((size_t)(cb * 16 + dt)) * 8192;
#pragma unroll
    for (int c = 0; c < 2; c++) {
      const int seg = (c * 4 + wv) * 1024;  // wave-uniform LDS dest; HW adds lane*16
      gll16((const char*)zh_s + zt + seg + lofs, (char*)smem + seg);
      gll16((const char*)wh_s + wt + seg + lofs, (char*)smem + 8192 + seg);
    }
    __syncthreads();  // compiler drains vmcnt before barrier
#pragma unroll
    for (int ks = 0; ks < 2; ks++) {
      const int ch = ks * 2 + lhi;
      const int ab = ch * 128 + wr * 64 + lrow;
      const int bb = 512 + ch * 128 + wc * 64 + lrow;
      f16x8 a0 = smem[ab], a1 = smem[ab + 32];
      f16x8 b0 = smem[bb], b1 = smem[bb + 32];
      acc[0][0] = MFMA16(a0, b0, acc[0][0]);
      acc[0][1] = MFMA16(a0, b1, acc[0][1]);
      acc[1][0] = MFMA16(a1, b0, acc[1][0]);
      acc[1][1] = MFMA16(a1, b1, acc[1][1]);
    }
  }

  // epilogue: approx relative distance (no zz; constant per row) + top-2 per
  // (row, 64-col wave half) via 5-step butterfly over the 32 lanes/row.
  const int c0 = cb * 128 + wc * 64 + lrow;
  const float ww0 = ww[c0], ww1 = ww[c0 + 32];
#pragma unroll
  for (int rf = 0; rf < 2; rf++) {
#pragma unroll
    for (int reg = 0; reg < 16; reg++) {
      // acc = dot(z, w*8192); d~ = ww - 2*dot
      float d0 = fmaf(acc[rf][0][reg], -2.44140625e-4f, ww0);
      float d1 = fmaf(acc[rf][1][reg], -2.44140625e-4f, ww1);
      int i0 = c0, i1 = c0 + 32;
      float p1d, p2d; int p1i, p2i;
      if (lexless(d1, i1, d0, i0)) { p1d = d1; p1i = i1; p2d = d0; p2i = i0; }
      else                         { p1d = d0; p1i = i0; p2d = d1; p2i = i1; }
#pragma unroll
      for (int m = 1; m <= 16; m <<= 1) {
        const float q1d = __shfl_xor(p1d, m, 64); const int q1i = __shfl_xor(p1i, m, 64);
        const float q2d = __shfl_xor(p2d, m, 64); const int q2i = __shfl_xor(p2i, m, 64);
        if (lexless(q1d, q1i, p1d, p1i)) {
          // top1 = q1; second = lexmin(p1, q2)
          if (lexless(q2d, q2i, p1d, p1i)) { p2d = q2d; p2i = q2i; }
          else                             { p2d = p1d; p2i = p1i; }
          p1d = q1d; p1i = q1i;
        } else {
          // top1 = p1; second = lexmin(q1, p2)
          if (lexless(q1d, q1i, p2d, p2i)) { p2d = q1d; p2i = q1i; }
        }
      }
      if (lrow == 0) {
        const int rloc = wr * 64 + rf * 32 + (reg & 3) + 8 * (reg >> 2) + 4 * lhi;
        const size_t o = ((size_t)(rb * 128 + rloc)) * 256 + (size_t)(cb * 2 + wc) * 2;
        bestd2[o] = p1d; bestd2[o + 1] = p2d;
        besti2[o] = p1i; besti2[o + 1] = p2i;
      }
    }
  }
}

// ---- stage 2: rescore survivors exactly + outputs. one wave per row ----
__global__ __launch_bounds__(256) void vq_rescore_kernel(
    const float* __restrict__ z, const float* __restrict__ W,
    const float* __restrict__ zz, const float* __restrict__ ww,
    const float* __restrict__ bestd2, const int* __restrict__ besti2,
    float* __restrict__ out, float* __restrict__ ws_f) {
  const int row  = (blockIdx.x * 256 + threadIdx.x) >> 6;
  const int lane = threadIdx.x & 63;
  const size_t base = (size_t)row * 256;
  const float4 dv = *(const float4*)&bestd2[base + lane * 4];
  const int4  iv = *(const int4*)&besti2[base + lane * 4];
  float dd[4] = {dv.x, dv.y, dv.z, dv.w};
  int   ii[4] = {iv.x, iv.y, iv.z, iv.w};

  float m = fminf(fminf(dd[0], dd[1]), fminf(dd[2], dd[3]));
#pragma unroll
  for (int mm = 1; mm <= 32; mm <<= 1) m = fminf(m, __shfl_xor(m, mm, 64));
  const float thr = m + EPS;

  const float* zp = z + (size_t)row * D_DIM;
  const float4 za = *(const float4*)&zp[lane * 8];
  const float4 zb = *(const float4*)&zp[lane * 8 + 4];
  const float zzr = zz[row];

  float bd = 3.4e38f; int bi = 0x7fffffff;
#pragma unroll
  for (int s = 0; s < 4; s++) {
    unsigned long long mset = __ballot(dd[s] <= thr);
    while (mset) {
      const int b = __ffsll((long long)mset) - 1;
      mset &= mset - 1;
      const int c = __shfl(ii[s], b, 64);
      const float* wp = W + (size_t)c * D_DIM;
      const float4 wa = *(const float4*)&wp[lane * 8];
      const float4 wb = *(const float4*)&wp[lane * 8 + 4];
      float dot = za.x*wa.x + za.y*wa.y + za.z*wa.z + za.w*wa.w
                + zb.x*wb.x + zb.y*wb.y + zb.z*wb.z + zb.w*wb.w;
#pragma unroll
      for (int mm = 1; mm <= 32; mm <<= 1) dot += __shfl_xor(dot, mm, 64);
      // exact reference rounding: (zz - 2*dot) + ww
      const float dist = (zzr - 2.0f * dot) + ww[c];
      if (dist < bd || (dist == bd && c < bi)) { bd = dist; bi = c; }
    }
  }

  if (lane == 0) {
    out[(size_t)N_ROWS * D_DIM + row] = (float)bi;
    atomicAdd(&ws_f[OFF_COUNTS + bi], 1.0f);  // integer-valued: order-independent
  }
  // quantize + loss (proven gather body)
  const float* wp = W + (size_t)bi * D_DIM;
  float* op = out + (size_t)row * D_DIM;
  float lsum = 0.f;
#pragma unroll
  for (int h = 0; h < 2; h++) {
    const int dd2 = h * 256 + lane * 4;
    const float4 zv = *(const float4*)&zp[dd2];
    const float4 wv = *(const float4*)&wp[dd2];
    float4 q;
    q.x = zv.x + (wv.x - zv.x);
    q.y = zv.y + (wv.y - zv.y);
    q.z = zv.z + (wv.z - zv.z);
    q.w = zv.w + (wv.w - zv.w);
    *(float4*)&op[dd2] = q;
    float dx;
    dx = zv.x - wv.x; lsum += dx * dx;
    dx = zv.y - wv.y; lsum += dx * dx;
    dx = zv.z - wv.z; lsum += dx * dx;
    dx = zv.w - wv.w; lsum += dx * dx;
  }
#pragma unroll
  for (int off = 32; off > 0; off >>= 1) lsum += __shfl_down(lsum, off, 64);
  __shared__ float lred[4];
  if (lane == 0) lred[threadIdx.x >> 6] = lsum;
  __syncthreads();
  if (threadIdx.x == 0)
    ws_f[OFF_PARTIAL + blockIdx.x] = lred[0] + lred[1] + lred[2] + lred[3];
}

// ================= fallback fp32 path (round-1, proven) =================
constexpr int BN = 64, BK = 64, BD = 32;
__global__ __launch_bounds__(256) void vq_dist_kernel(
    const float* __restrict__ z, const float* __restrict__ W,
    const float* __restrict__ zz, const float* __restrict__ ww,
    float* __restrict__ bestd_out, int* __restrict__ besti_out) {
  __shared__ float zs[BD][68];
  __shared__ float ws_[BD][68];
  __shared__ float rd[BN][16];
  __shared__ int   ri[BN][16];
  const int tid = threadIdx.x;
  const int tx = tid & 15;
  const int ty = tid >> 4;
  const int r0 = blockIdx.x * BN;
  const int kbase0 = blockIdx.y * KSPL;
  const int lr = tid >> 3;
  const int lc = tid & 7;
  float bd[4]; int bi[4];
#pragma unroll
  for (int i = 0; i < 4; i++) { bd[i] = 3.4e38f; bi[i] = 0x7fffffff; }
  float zzr[4];
#pragma unroll
  for (int i = 0; i < 4; i++) zzr[i] = zz[r0 + ty * 4 + i];
  for (int kt = 0; kt < KSPL; kt += BK) {
    const int kb = kbase0 + kt;
    float c[4][4];
#pragma unroll
    for (int i = 0; i < 4; i++)
#pragma unroll
      for (int j = 0; j < 4; j++) c[i][j] = 0.f;
    for (int dtt = 0; dtt < D_DIM; dtt += BD) {
#pragma unroll
      for (int h = 0; h < 2; h++) {
        const int r = lr + h * 32;
        const float4 v = *(const float4*)&z[(size_t)(r0 + r) * D_DIM + dtt + lc * 4];
        zs[lc*4+0][r] = v.x; zs[lc*4+1][r] = v.y; zs[lc*4+2][r] = v.z; zs[lc*4+3][r] = v.w;
        const float4 u = *(const float4*)&W[(size_t)(kb + r) * D_DIM + dtt + lc * 4];
        ws_[lc*4+0][r] = u.x; ws_[lc*4+1][r] = u.y; ws_[lc*4+2][r] = u.z; ws_[lc*4+3][r] = u.w;
      }
      __syncthreads();
#pragma unroll
      for (int d = 0; d < BD; d++) {
        const float4 a = *(const float4*)&zs[d][ty * 4];
        const float4 b = *(const float4*)&ws_[d][tx * 4];
        c[0][0] += a.x*b.x; c[0][1] += a.x*b.y; c[0][2] += a.x*b.z; c[0][3] += a.x*b.w;
        c[1][0] += a.y*b.x; c[1][1] += a.y*b.y; c[1][2] += a.y*b.z; c[1][3] += a.y*b.w;
        c[2][0] += a.z*b.x; c[2][1] += a.z*b.y; c[2][2] += a.z*b.z; c[2][3] += a.z*b.w;
        c[3][0] += a.w*b.x; c[3][1] += a.w*b.y; c[3][2] += a.w*b.z; c[3][3] += a.w*b.w;
      }
      __syncthreads();
    }
#pragma unroll
    for (int i = 0; i < 4; i++) {
#pragma unroll
      for (int j = 0; j < 4; j++) {
        const int col = kb + tx * 4 + j;
        const float dist = (zzr[i] - 2.0f * c[i][j]) + ww[col];
        if (dist < bd[i]) { bd[i] = dist; bi[i] = col; }
      }
    }
  }
#pragma unroll
  for (int i = 0; i < 4; i++) { rd[ty * 4 + i][tx] = bd[i]; ri[ty * 4 + i][tx] = bi[i]; }
  __syncthreads();
  if (tid < BN) {
    float best = rd[tid][0]; int bidx = ri[tid][0];
#pragma unroll
    for (int t = 1; t < 16; t++) {
      const float dv = rd[tid][t]; const int iv = ri[tid][t];
      if (dv < best || (dv == best && iv < bidx)) { best = dv; bidx = iv; }
    }
    bestd_out[(size_t)blockIdx.y * N_ROWS + r0 + tid] = best;
    besti_out[(size_t)blockIdx.y * N_ROWS + r0 + tid] = bidx;
  }
}

__global__ __launch_bounds__(256) void vq_gather8_kernel(
    const float* __restrict__ z, const float* __restrict__ W,
    const float* __restrict__ bestd, const int* __restrict__ besti,
    float* __restrict__ out, float* __restrict__ ws_f) {
  const int row  = (blockIdx.x * 256 + threadIdx.x) >> 6;
  const int lane = threadIdx.x & 63;
  int bidx = 0;
  if (lane == 0) {
    float best = bestd[row];
    bidx = besti[row];
#pragma unroll
    for (int s = 1; s < SPLITK; s++) {
      const float dv = bestd[(size_t)s * N_ROWS + row];
      const int iv = besti[(size_t)s * N_ROWS + row];
      if (dv < best || (dv == best && iv < bidx)) { best = dv; bidx = iv; }
    }
    out[(size_t)N_ROWS * D_DIM + row] = (float)bidx;
    atomicAdd(&ws_f[OFF_COUNTS + bidx], 1.0f);
  }
  bidx = __shfl(bidx, 0, 64);
  const float* zp = z + (size_t)row * D_DIM;
  const float* wp = W + (size_t)bidx * D_DIM;
  float* op = out + (size_t)row * D_DIM;
  float lsum = 0.f;
#pragma unroll
  for (int h = 0; h < 2; h++) {
    const int d = h * 256 + lane * 4;
    const float4 zv = *(const float4*)&zp[d];
    const float4 wv = *(const float4*)&wp[d];
    float4 q;
    q.x = zv.x + (wv.x - zv.x);
    q.y = zv.y + (wv.y - zv.y);
    q.z = zv.z + (wv.z - zv.z);
    q.w = zv.w + (wv.w - zv.w);
    *(float4*)&op[d] = q;
    float dx;
    dx = zv.x - wv.x; lsum += dx * dx;
    dx = zv.y - wv.y; lsum += dx * dx;
    dx = zv.z - wv.z; lsum += dx * dx;
    dx = zv.w - wv.w; lsum += dx * dx;
  }
#pragma unroll
  for (int off = 32; off > 0; off >>= 1) lsum += __shfl_down(lsum, off, 64);
  if (lane == 0) atomicAdd(&ws_f[OFF_LOSS], lsum);
}

// ---- finalize: loss scalar + perplexity ----
__global__ __launch_bounds__(256) void vq_finalize_kernel(const float* __restrict__ ws_f,
                                                          float* __restrict__ out,
                                                          int use_partial) {
  const int tid = threadIdx.x;
  float ls = 0.f;
  if (use_partial) {
    for (int i = tid; i < 2048; i += 256) ls += ws_f[OFF_PARTIAL + i];
  }
  float s = 0.f;
  for (int k = tid; k < K_CODES; k += 256) {
    const float p = ws_f[OFF_COUNTS + k] * (1.0f / 8192.0f);
    s += p * logf(p + 1e-10f);
  }
#pragma unroll
  for (int off = 32; off > 0; off >>= 1) {
    s  += __shfl_down(s, off, 64);
    ls += __shfl_down(ls, off, 64);
  }
  __shared__ float red[4], redl[4];
  if ((tid & 63) == 0) { red[tid >> 6] = s; redl[tid >> 6] = ls; }
  __syncthreads();
  if (tid == 0) {
    const float tot = red[0] + red[1] + red[2] + red[3];
    const float L = use_partial ? (redl[0] + redl[1] + redl[2] + redl[3])
                                : ws_f[OFF_LOSS];
    out[(size_t)N_ROWS * D_DIM + N_ROWS]     = COMMIT * (L / 4194304.0f);
    out[(size_t)N_ROWS * D_DIM + N_ROWS + 1] = expf(-tot);
  }
}

extern "C" void kernel_launch(void* const* d_in, const int* in_sizes, int n_in,
                              void* d_out, int out_size, void* d_ws, size_t ws_size,
                              hipStream_t stream) {
  const float* z = (const float*)d_in[0];
  const float* W = (const float*)d_in[1];
  float* out = (float*)d_out;
  float* ws_f = (float*)d_ws;
  int* ws_i = (int*)d_ws;

  hipMemsetAsync(d_ws, 0, (OFF_COUNTS + K_CODES) * sizeof(float), stream);

  rowss_kernel<<<N_ROWS / 4, 256, 0, stream>>>(z, ws_f + OFF_ZZ);
  rowss_kernel<<<K_CODES / 4, 256, 0, stream>>>(W, ws_f + OFF_WW);

  if (ws_size >= WS_NEED) {
    unsigned short* zh = (unsigned short*)((char*)d_ws + F16_BASE_BYTES);
    unsigned short* wh = zh + SPLIT_ELEMS;
    split_hi_kernel<<<dim3(16, 64), 256, 0, stream>>>(z, zh, 1.0f);
    split_hi_kernel<<<dim3(16, 64), 256, 0, stream>>>(W, wh, 8192.0f);
    vq_screen_kernel<<<dim3(64, 64), 256, 0, stream>>>(
        zh, wh, ws_f + OFF_WW, ws_f + OFF_BESTD, ws_i + OFF_BESTI);
    vq_rescore_kernel<<<N_ROWS / 4, 256, 0, stream>>>(
        z, W, ws_f + OFF_ZZ, ws_f + OFF_WW,
        ws_f + OFF_BESTD, ws_i + OFF_BESTI, out, ws_f);
    vq_finalize_kernel<<<1, 256, 0, stream>>>(ws_f, out, 1);
  } else {
    dim3 grid(N_ROWS / BN, SPLITK);
    vq_dist_kernel<<<grid, 256, 0, stream>>>(z, W, ws_f + OFF_ZZ, ws_f + OFF_WW,
                                             ws_f + OFF_BESTD, ws_i + OFF_BESTI);
    vq_gather8_kernel<<<N_ROWS / 4, 256, 0, stream>>>(z, W, ws_f + OFF_BESTD,
                                                      ws_i + OFF_BESTI, out, ws_f);
    vq_finalize_kernel<<<1, 256, 0, stream>>>(ws_f, out, 0);
  }
}

// Round 6
// 216.823 us; speedup vs baseline: 5.3966x; 1.4324x over previous
//
#include <hip/hip_runtime.h>
#include <math.h>

// VQ-VAE eval forward: z [4,2048,512] f32, W [8192,512] f32.
// Outputs (flat f32): quantized [4194304], indices [8192], loss [1], perplexity [1].
//
// Fast path (two-stage):
//   1) screen: f16 hh-only MFMA GEMM, all-register (no LDS, no barriers),
//      swapped operands (reg->code, lane->zrow) so top-2-per-64-codes is an
//      in-register chain + one shfl_xor(32) merge.
//   2) rescore: exact fp32 reference-rounded distance for all candidates within
//      EPS of the row's approx min; fused with quantize/loss/counts outputs.
// Fallback: round-1 fp32 VALU kernel (correctness-proven).

typedef __attribute__((ext_vector_type(8))) _Float16 f16x8;
typedef __attribute__((ext_vector_type(16))) float f32x16;

constexpr int N_ROWS = 8192;   // 4*2048
constexpr int K_CODES = 8192;
constexpr int D_DIM = 512;
constexpr float COMMIT = 0.25f;
// screen-vs-reference pairwise offset bound ~1.9e-4 (f16 hh error 3.2e-5 + fl
// quantization 6.1e-5, pairwise x2); EPS = 3e-4 gives >1.5x margin while
// keeping expected survivors ~1.1/row.
constexpr float EPS = 3.0e-4f;

// ---- workspace layout (float offsets) ----
constexpr size_t OFF_LOSS    = 0;
constexpr size_t OFF_COUNTS  = 64;         // 8192 floats
constexpr size_t OFF_PARTIAL = 8256;       // 2048 floats (per-block loss partials)
constexpr size_t OFF_ZZ      = 16384;      // 8192 floats
constexpr size_t OFF_WW      = 24576;      // 8192 floats
constexpr size_t OFF_BESTD   = 32768;      // fast: [8192 rows][256]; fallback: [8][8192]
constexpr size_t OFF_BESTI   = 2129920;    // ints, same shapes
constexpr size_t F16_BASE_BYTES = 16908288; // = (2129920 + 2097152) * 4
constexpr size_t SPLIT_ELEMS = (size_t)8192 * 512;
constexpr size_t SPLIT_BYTES = SPLIT_ELEMS * 2;           // 8 MB each
constexpr size_t WS_NEED = F16_BASE_BYTES + 2 * SPLIT_BYTES; // 33,685,504 B

constexpr int SPLITK = 8;
constexpr int KSPL = K_CODES / SPLITK;

#define MFMA16(a, b, c) __builtin_amdgcn_mfma_f32_32x32x16_f16((a), (b), (c), 0, 0, 0)

// ---- row sum-of-squares: one wave per row of a [R][512] matrix ----
__global__ __launch_bounds__(256) void rowss_kernel(const float* __restrict__ src,
                                                    float* __restrict__ dst) {
  int row  = (blockIdx.x * 256 + threadIdx.x) >> 6;
  int lane = threadIdx.x & 63;
  const float* p = src + (size_t)row * D_DIM;
  float4 a = *(const float4*)&p[lane * 4];
  float4 b = *(const float4*)&p[256 + lane * 4];
  float s = a.x*a.x + a.y*a.y + a.z*a.z + a.w*a.w
          + b.x*b.x + b.y*b.y + b.z*b.z + b.w*b.w;
#pragma unroll
  for (int off = 32; off > 0; off >>= 1) s += __shfl_down(s, off, 64);
  if (lane == 0) dst[row] = s;
}

// ---- prepass: f32 -> f16 hi part, tiled [tile][chunk4][row128][8] ----
__global__ __launch_bounds__(256) void split_hi_kernel(const float* __restrict__ src,
                                                       unsigned short* __restrict__ hi,
                                                       float scale) {
  const int dt = blockIdx.x;
  const int rb = blockIdx.y;
  const int t = threadIdx.x;
  const int row = t >> 1;
  const int dh = (t & 1) * 16;
  const float* sp = src + ((size_t)(rb * 128 + row)) * D_DIM + dt * 32 + dh;
  const float4* sp4 = (const float4*)sp;
  float4 va = sp4[0], vb = sp4[1], vc = sp4[2], vd = sp4[3];
  float v[16] = {va.x, va.y, va.z, va.w, vb.x, vb.y, vb.z, vb.w,
                 vc.x, vc.y, vc.z, vc.w, vd.x, vd.y, vd.z, vd.w};
  const size_t tile = (size_t)(rb * 16 + dt) * 4096;
#pragma unroll
  for (int c2 = 0; c2 < 2; c2++) {
    const int chunk = (t & 1) * 2 + c2;
    f16x8 hv;
#pragma unroll
    for (int j = 0; j < 8; j++) hv[j] = (_Float16)(v[c2 * 8 + j] * scale);
    *(f16x8*)(hi + tile + (size_t)chunk * 1024 + (size_t)row * 8) = hv;
  }
}

// ---- stage 1: screen. all-register, swapped operands, top-2 per (row, 64 codes) ----
// grid (64 cb, 64 rb), block 256 (4 waves 2x2: wr=code-half, wc=zrow-half).
__global__ __launch_bounds__(256, 3) void vq_screen_kernel(
    const unsigned short* __restrict__ zh_s, const unsigned short* __restrict__ wh_s,
    const float* __restrict__ ww,
    float* __restrict__ bestd2, int* __restrict__ besti2) {
  const int tid = threadIdx.x;
  const int cb = blockIdx.x, rb = blockIdx.y;
  const int lane = tid & 63, wv = tid >> 6;
  const int wr = wv >> 1, wc = wv & 1;
  const int lrow = lane & 31, lhi = lane >> 5;

  const f16x8* zh8 = (const f16x8*)zh_s;
  const f16x8* wh8 = (const f16x8*)wh_s;

  // acc[rf][cf]: rf = 32-code fragment (A=W), cf = 32-zrow fragment (B=Z)
  // C/D layout: code = wr*64 + rf*32 + (reg&3)+8*(reg>>2)+4*lhi ; zrow = wc*64 + cf*32 + lrow
  f32x16 acc[2][2];
#pragma unroll
  for (int i = 0; i < 2; i++)
#pragma unroll
    for (int j = 0; j < 2; j++)
#pragma unroll
      for (int e = 0; e < 16; e++) acc[i][j][e] = 0.0f;

  const int wbase = wr * 64 + lrow;
  const int zbase = wc * 64 + lrow;

#pragma unroll 2
  for (int dt = 0; dt < 16; dt++) {
    const int wt = (cb * 16 + dt) * 512;  // f16x8 units
    const int zt = (rb * 16 + dt) * 512;
    f16x8 wf[2][2], zf[2][2];  // [ks][rf / cf]
#pragma unroll
    for (int ks = 0; ks < 2; ks++) {
      const int ch = ks * 2 + lhi;
      wf[ks][0] = wh8[wt + ch * 128 + wbase];
      wf[ks][1] = wh8[wt + ch * 128 + wbase + 32];
      zf[ks][0] = zh8[zt + ch * 128 + zbase];
      zf[ks][1] = zh8[zt + ch * 128 + zbase + 32];
    }
    __builtin_amdgcn_s_setprio(1);
#pragma unroll
    for (int ks = 0; ks < 2; ks++) {
      acc[0][0] = MFMA16(wf[ks][0], zf[ks][0], acc[0][0]);
      acc[0][1] = MFMA16(wf[ks][0], zf[ks][1], acc[0][1]);
      acc[1][0] = MFMA16(wf[ks][1], zf[ks][0], acc[1][0]);
      acc[1][1] = MFMA16(wf[ks][1], zf[ks][1], acc[1][1]);
    }
    __builtin_amdgcn_s_setprio(0);
  }

  // epilogue: per lane in-register top-2 over its 32 codes, then one xor-32 merge.
  // acc = dot(z, w*8192); d~ = ww - 2*dot = fmaf(acc, -2^-12, ww)
#pragma unroll
  for (int cf = 0; cf < 2; cf++) {
    float p1d = 3.4e38f, p2d = 3.4e38f;
    int   p1i = 0x7fffffff, p2i = 0x7fffffff;
#pragma unroll
    for (int rf = 0; rf < 2; rf++) {
      const int cbase = cb * 128 + wr * 64 + rf * 32 + 4 * lhi;
#pragma unroll
      for (int reg = 0; reg < 16; reg++) {
        const int ci = cbase + (reg & 3) + 8 * (reg >> 2);
        const float d = fmaf(acc[rf][cf][reg], -2.44140625e-4f, ww[ci]);
        // plain-compare top-2 (ties corrected by exact rescore)
        const bool b1 = d < p1d;
        const bool b2 = d < p2d;
        p2d = b1 ? p1d : (b2 ? d : p2d);
        p2i = b1 ? p1i : (b2 ? ci : p2i);
        p1d = b1 ? d : p1d;
        p1i = b1 ? ci : p1i;
      }
    }
    // merge with complementary lane (same zrow, other 16-code parity set)
    const float q1d = __shfl_xor(p1d, 32, 64); const int q1i = __shfl_xor(p1i, 32, 64);
    const float q2d = __shfl_xor(p2d, 32, 64); const int q2i = __shfl_xor(p2i, 32, 64);
    float t1d, t2d; int t1i, t2i;
    if (q1d < p1d) {
      t1d = q1d; t1i = q1i;
      if (p1d < q2d) { t2d = p1d; t2i = p1i; } else { t2d = q2d; t2i = q2i; }
    } else {
      t1d = p1d; t1i = p1i;
      if (q1d < p2d) { t2d = q1d; t2i = q1i; } else { t2d = p2d; t2i = p2i; }
    }
    if (lhi == 0) {
      const int row = rb * 128 + wc * 64 + cf * 32 + lrow;
      const size_t o = (size_t)row * 256 + (size_t)(cb * 2 + wr) * 2;
      float2 dv2; dv2.x = t1d; dv2.y = t2d;
      int2   iv2; iv2.x = t1i; iv2.y = t2i;
      *(float2*)&bestd2[o] = dv2;
      *(int2*)&besti2[o]   = iv2;
    }
  }
}

// ---- stage 2: rescore survivors exactly + outputs. one wave per row ----
__global__ __launch_bounds__(256) void vq_rescore_kernel(
    const float* __restrict__ z, const float* __restrict__ W,
    const float* __restrict__ zz, const float* __restrict__ ww,
    const float* __restrict__ bestd2, const int* __restrict__ besti2,
    float* __restrict__ out, float* __restrict__ ws_f) {
  const int row  = (blockIdx.x * 256 + threadIdx.x) >> 6;
  const int lane = threadIdx.x & 63;
  const size_t base = (size_t)row * 256;
  const float4 dv = *(const float4*)&bestd2[base + lane * 4];
  const int4  iv = *(const int4*)&besti2[base + lane * 4];
  float dd[4] = {dv.x, dv.y, dv.z, dv.w};
  int   ii[4] = {iv.x, iv.y, iv.z, iv.w};

  float m = fminf(fminf(dd[0], dd[1]), fminf(dd[2], dd[3]));
#pragma unroll
  for (int mm = 1; mm <= 32; mm <<= 1) m = fminf(m, __shfl_xor(m, mm, 64));
  const float thr = m + EPS;

  const float* zp = z + (size_t)row * D_DIM;
  const float4 za = *(const float4*)&zp[lane * 8];
  const float4 zb = *(const float4*)&zp[lane * 8 + 4];
  const float zzr = zz[row];

  float bd = 3.4e38f; int bi = 0x7fffffff;
#pragma unroll
  for (int s = 0; s < 4; s++) {
    unsigned long long mset = __ballot(dd[s] <= thr);
    while (mset) {
      const int b = __ffsll((long long)mset) - 1;
      mset &= mset - 1;
      const int c = __shfl(ii[s], b, 64);
      const float* wp = W + (size_t)c * D_DIM;
      const float4 wa = *(const float4*)&wp[lane * 8];
      const float4 wb = *(const float4*)&wp[lane * 8 + 4];
      float dot = za.x*wa.x + za.y*wa.y + za.z*wa.z + za.w*wa.w
                + zb.x*wb.x + zb.y*wb.y + zb.z*wb.z + zb.w*wb.w;
#pragma unroll
      for (int mm = 1; mm <= 32; mm <<= 1) dot += __shfl_xor(dot, mm, 64);
      // exact reference rounding: (zz - 2*dot) + ww
      const float dist = (zzr - 2.0f * dot) + ww[c];
      if (dist < bd || (dist == bd && c < bi)) { bd = dist; bi = c; }
    }
  }

  if (lane == 0) {
    out[(size_t)N_ROWS * D_DIM + row] = (float)bi;
    atomicAdd(&ws_f[OFF_COUNTS + bi], 1.0f);  // integer-valued: order-independent
  }
  // quantize + loss (proven gather body)
  const float* wp = W + (size_t)bi * D_DIM;
  float* op = out + (size_t)row * D_DIM;
  float lsum = 0.f;
#pragma unroll
  for (int h = 0; h < 2; h++) {
    const int dd2 = h * 256 + lane * 4;
    const float4 zv = *(const float4*)&zp[dd2];
    const float4 wv = *(const float4*)&wp[dd2];
    float4 q;
    q.x = zv.x + (wv.x - zv.x);
    q.y = zv.y + (wv.y - zv.y);
    q.z = zv.z + (wv.z - zv.z);
    q.w = zv.w + (wv.w - zv.w);
    *(float4*)&op[dd2] = q;
    float dx;
    dx = zv.x - wv.x; lsum += dx * dx;
    dx = zv.y - wv.y; lsum += dx * dx;
    dx = zv.z - wv.z; lsum += dx * dx;
    dx = zv.w - wv.w; lsum += dx * dx;
  }
#pragma unroll
  for (int off = 32; off > 0; off >>= 1) lsum += __shfl_down(lsum, off, 64);
  __shared__ float lred[4];
  if (lane == 0) lred[threadIdx.x >> 6] = lsum;
  __syncthreads();
  if (threadIdx.x == 0)
    ws_f[OFF_PARTIAL + blockIdx.x] = lred[0] + lred[1] + lred[2] + lred[3];
}

// ================= fallback fp32 path (round-1, proven) =================
constexpr int BN = 64, BK = 64, BD = 32;
__global__ __launch_bounds__(256) void vq_dist_kernel(
    const float* __restrict__ z, const float* __restrict__ W,
    const float* __restrict__ zz, const float* __restrict__ ww,
    float* __restrict__ bestd_out, int* __restrict__ besti_out) {
  __shared__ float zs[BD][68];
  __shared__ float ws_[BD][68];
  __shared__ float rd[BN][16];
  __shared__ int   ri[BN][16];
  const int tid = threadIdx.x;
  const int tx = tid & 15;
  const int ty = tid >> 4;
  const int r0 = blockIdx.x * BN;
  const int kbase0 = blockIdx.y * KSPL;
  const int lr = tid >> 3;
  const int lc = tid & 7;
  float bd[4]; int bi[4];
#pragma unroll
  for (int i = 0; i < 4; i++) { bd[i] = 3.4e38f; bi[i] = 0x7fffffff; }
  float zzr[4];
#pragma unroll
  for (int i = 0; i < 4; i++) zzr[i] = zz[r0 + ty * 4 + i];
  for (int kt = 0; kt < KSPL; kt += BK) {
    const int kb = kbase0 + kt;
    float c[4][4];
#pragma unroll
    for (int i = 0; i < 4; i++)
#pragma unroll
      for (int j = 0; j < 4; j++) c[i][j] = 0.f;
    for (int dtt = 0; dtt < D_DIM; dtt += BD) {
#pragma unroll
      for (int h = 0; h < 2; h++) {
        const int r = lr + h * 32;
        const float4 v = *(const float4*)&z[(size_t)(r0 + r) * D_DIM + dtt + lc * 4];
        zs[lc*4+0][r] = v.x; zs[lc*4+1][r] = v.y; zs[lc*4+2][r] = v.z; zs[lc*4+3][r] = v.w;
        const float4 u = *(const float4*)&W[(size_t)(kb + r) * D_DIM + dtt + lc * 4];
        ws_[lc*4+0][r] = u.x; ws_[lc*4+1][r] = u.y; ws_[lc*4+2][r] = u.z; ws_[lc*4+3][r] = u.w;
      }
      __syncthreads();
#pragma unroll
      for (int d = 0; d < BD; d++) {
        const float4 a = *(const float4*)&zs[d][ty * 4];
        const float4 b = *(const float4*)&ws_[d][tx * 4];
        c[0][0] += a.x*b.x; c[0][1] += a.x*b.y; c[0][2] += a.x*b.z; c[0][3] += a.x*b.w;
        c[1][0] += a.y*b.x; c[1][1] += a.y*b.y; c[1][2] += a.y*b.z; c[1][3] += a.y*b.w;
        c[2][0] += a.z*b.x; c[2][1] += a.z*b.y; c[2][2] += a.z*b.z; c[2][3] += a.z*b.w;
        c[3][0] += a.w*b.x; c[3][1] += a.w*b.y; c[3][2] += a.w*b.z; c[3][3] += a.w*b.w;
      }
      __syncthreads();
    }
#pragma unroll
    for (int i = 0; i < 4; i++) {
#pragma unroll
      for (int j = 0; j < 4; j++) {
        const int col = kb + tx * 4 + j;
        const float dist = (zzr[i] - 2.0f * c[i][j]) + ww[col];
        if (dist < bd[i]) { bd[i] = dist; bi[i] = col; }
      }
    }
  }
#pragma unroll
  for (int i = 0; i < 4; i++) { rd[ty * 4 + i][tx] = bd[i]; ri[ty * 4 + i][tx] = bi[i]; }
  __syncthreads();
  if (tid < BN) {
    float best = rd[tid][0]; int bidx = ri[tid][0];
#pragma unroll
    for (int t = 1; t < 16; t++) {
      const float dv = rd[tid][t]; const int iv = ri[tid][t];
      if (dv < best || (dv == best && iv < bidx)) { best = dv; bidx = iv; }
    }
    bestd_out[(size_t)blockIdx.y * N_ROWS + r0 + tid] = best;
    besti_out[(size_t)blockIdx.y * N_ROWS + r0 + tid] = bidx;
  }
}

__global__ __launch_bounds__(256) void vq_gather8_kernel(
    const float* __restrict__ z, const float* __restrict__ W,
    const float* __restrict__ bestd, const int* __restrict__ besti,
    float* __restrict__ out, float* __restrict__ ws_f) {
  const int row  = (blockIdx.x * 256 + threadIdx.x) >> 6;
  const int lane = threadIdx.x & 63;
  int bidx = 0;
  if (lane == 0) {
    float best = bestd[row];
    bidx = besti[row];
#pragma unroll
    for (int s = 1; s < SPLITK; s++) {
      const float dv = bestd[(size_t)s * N_ROWS + row];
      const int iv = besti[(size_t)s * N_ROWS + row];
      if (dv < best || (dv == best && iv < bidx)) { best = dv; bidx = iv; }
    }
    out[(size_t)N_ROWS * D_DIM + row] = (float)bidx;
    atomicAdd(&ws_f[OFF_COUNTS + bidx], 1.0f);
  }
  bidx = __shfl(bidx, 0, 64);
  const float* zp = z + (size_t)row * D_DIM;
  const float* wp = W + (size_t)bidx * D_DIM;
  float* op = out + (size_t)row * D_DIM;
  float lsum = 0.f;
#pragma unroll
  for (int h = 0; h < 2; h++) {
    const int d = h * 256 + lane * 4;
    const float4 zv = *(const float4*)&zp[d];
    const float4 wv = *(const float4*)&wp[d];
    float4 q;
    q.x = zv.x + (wv.x - zv.x);
    q.y = zv.y + (wv.y - zv.y);
    q.z = zv.z + (wv.z - zv.z);
    q.w = zv.w + (wv.w - zv.w);
    *(float4*)&op[d] = q;
    float dx;
    dx = zv.x - wv.x; lsum += dx * dx;
    dx = zv.y - wv.y; lsum += dx * dx;
    dx = zv.z - wv.z; lsum += dx * dx;
    dx = zv.w - wv.w; lsum += dx * dx;
  }
#pragma unroll
  for (int off = 32; off > 0; off >>= 1) lsum += __shfl_down(lsum, off, 64);
  if (lane == 0) atomicAdd(&ws_f[OFF_LOSS], lsum);
}

// ---- finalize: loss scalar + perplexity ----
__global__ __launch_bounds__(256) void vq_finalize_kernel(const float* __restrict__ ws_f,
                                                          float* __restrict__ out,
                                                          int use_partial) {
  const int tid = threadIdx.x;
  float ls = 0.f;
  if (use_partial) {
    for (int i = tid; i < 2048; i += 256) ls += ws_f[OFF_PARTIAL + i];
  }
  float s = 0.f;
  for (int k = tid; k < K_CODES; k += 256) {
    const float p = ws_f[OFF_COUNTS + k] * (1.0f / 8192.0f);
    s += p * logf(p + 1e-10f);
  }
#pragma unroll
  for (int off = 32; off > 0; off >>= 1) {
    s  += __shfl_down(s, off, 64);
    ls += __shfl_down(ls, off, 64);
  }
  __shared__ float red[4], redl[4];
  if ((tid & 63) == 0) { red[tid >> 6] = s; redl[tid >> 6] = ls; }
  __syncthreads();
  if (tid == 0) {
    const float tot = red[0] + red[1] + red[2] + red[3];
    const float L = use_partial ? (redl[0] + redl[1] + redl[2] + redl[3])
                                : ws_f[OFF_LOSS];
    out[(size_t)N_ROWS * D_DIM + N_ROWS]     = COMMIT * (L / 4194304.0f);
    out[(size_t)N_ROWS * D_DIM + N_ROWS + 1] = expf(-tot);
  }
}

extern "C" void kernel_launch(void* const* d_in, const int* in_sizes, int n_in,
                              void* d_out, int out_size, void* d_ws, size_t ws_size,
                              hipStream_t stream) {
  const float* z = (const float*)d_in[0];
  const float* W = (const float*)d_in[1];
  float* out = (float*)d_out;
  float* ws_f = (float*)d_ws;
  int* ws_i = (int*)d_ws;

  hipMemsetAsync(d_ws, 0, (OFF_COUNTS + K_CODES) * sizeof(float), stream);

  rowss_kernel<<<N_ROWS / 4, 256, 0, stream>>>(z, ws_f + OFF_ZZ);
  rowss_kernel<<<K_CODES / 4, 256, 0, stream>>>(W, ws_f + OFF_WW);

  if (ws_size >= WS_NEED) {
    unsigned short* zh = (unsigned short*)((char*)d_ws + F16_BASE_BYTES);
    unsigned short* wh = zh + SPLIT_ELEMS;
    split_hi_kernel<<<dim3(16, 64), 256, 0, stream>>>(z, zh, 1.0f);
    split_hi_kernel<<<dim3(16, 64), 256, 0, stream>>>(W, wh, 8192.0f);
    vq_screen_kernel<<<dim3(64, 64), 256, 0, stream>>>(
        zh, wh, ws_f + OFF_WW, ws_f + OFF_BESTD, ws_i + OFF_BESTI);
    vq_rescore_kernel<<<N_ROWS / 4, 256, 0, stream>>>(
        z, W, ws_f + OFF_ZZ, ws_f + OFF_WW,
        ws_f + OFF_BESTD, ws_i + OFF_BESTI, out, ws_f);
    vq_finalize_kernel<<<1, 256, 0, stream>>>(ws_f, out, 1);
  } else {
    dim3 grid(N_ROWS / BN, SPLITK);
    vq_dist_kernel<<<grid, 256, 0, stream>>>(z, W, ws_f + OFF_ZZ, ws_f + OFF_WW,
                                             ws_f + OFF_BESTD, ws_i + OFF_BESTI);
    vq_gather8_kernel<<<N_ROWS / 4, 256, 0, stream>>>(z, W, ws_f + OFF_BESTD,
                                                      ws_i + OFF_BESTI, out, ws_f);
    vq_finalize_kernel<<<1, 256, 0, stream>>>(ws_f, out, 0);
  }
}

// Round 7
// 216.704 us; speedup vs baseline: 5.3996x; 1.0005x over previous
//
#include <hip/hip_runtime.h>
#include <math.h>

// VQ-VAE eval forward: z [4,2048,512] f32, W [8192,512] f32.
// Outputs (flat f32): quantized [4194304], indices [8192], loss [1], perplexity [1].
//
// Fast path (two-stage):
//   0) prep: fused zero + row-norms + f32->f16 tiling for z and W (1 kernel).
//   1) screen: f16 hh-only MFMA GEMM, all-register, double-buffered register
//      prefetch, XCD super-tile swizzle; top-2 per (row, 64 codes).
//   2) rescore: exact fp32 reference-rounded distance for all candidates within
//      EPS of the row's approx min; fused with quantize/loss/counts outputs.
// Fallback: round-1 fp32 VALU kernel (correctness-proven).

typedef __attribute__((ext_vector_type(8))) _Float16 f16x8;
typedef __attribute__((ext_vector_type(16))) float f32x16;

constexpr int N_ROWS = 8192;   // 4*2048
constexpr int K_CODES = 8192;
constexpr int D_DIM = 512;
constexpr float COMMIT = 0.25f;
// screen-vs-reference pairwise offset bound ~1.9e-4 (f16 hh error 3.2e-5 + fl
// quantization 6.1e-5, pairwise x2); EPS = 3e-4 gives >1.5x margin while
// keeping expected survivors ~1.1/row.
constexpr float EPS = 3.0e-4f;

// ---- workspace layout (float offsets) ----
constexpr size_t OFF_LOSS    = 0;
constexpr size_t OFF_COUNTS  = 64;         // 8192 floats
constexpr size_t OFF_PARTIAL = 8256;       // 2048 floats (per-block loss partials)
constexpr size_t OFF_ZZ      = 16384;      // 8192 floats
constexpr size_t OFF_WW      = 24576;      // 8192 floats
constexpr size_t OFF_BESTD   = 32768;      // fast: [8192 rows][256]; fallback: [8][8192]
constexpr size_t OFF_BESTI   = 2129920;    // ints, same shapes
constexpr size_t F16_BASE_BYTES = 16908288; // = (2129920 + 2097152) * 4
constexpr size_t SPLIT_ELEMS = (size_t)8192 * 512;
constexpr size_t SPLIT_BYTES = SPLIT_ELEMS * 2;           // 8 MB each
constexpr size_t WS_NEED = F16_BASE_BYTES + 2 * SPLIT_BYTES; // 33,685,504 B

constexpr int SPLITK = 8;
constexpr int KSPL = K_CODES / SPLITK;

#define MFMA16(a, b, c) __builtin_amdgcn_mfma_f32_32x32x16_f16((a), (b), (c), 0, 0, 0)

__device__ __forceinline__ bool lexless(float da, int ia, float db, int ib) {
  return da < db || (da == db && ia < ib);
}

// ---- fast-path prep: zero ws accumulators + row sum-of-squares + f16 tiles ----
// grid (128, 2): x = 64-row block, y = src (0=z scale 1, 1=W scale 8192).
// 256 threads: row = bx*64 + (tid>>2); q = tid&3 covers dims [q*128, q*128+128).
__global__ __launch_bounds__(256) void prep_kernel(
    const float* __restrict__ z, const float* __restrict__ W,
    unsigned short* __restrict__ zh, unsigned short* __restrict__ wh,
    float* __restrict__ ws_f) {
  const int src = blockIdx.y;
  const int tid = threadIdx.x;
  // zero [0, 10304) floats: loss + counts + partials (disjoint from ZZ/WW)
  if (src == 0 && blockIdx.x < 11) {
#pragma unroll
    for (int k = 0; k < 4; k++) {
      const int idx = blockIdx.x * 1024 + k * 256 + tid;
      if (idx < 10304) ws_f[idx] = 0.0f;
    }
  }
  const float* S = src ? W : z;
  unsigned short* H = src ? wh : zh;
  const float scale = src ? 8192.0f : 1.0f;
  float* norm = ws_f + (src ? OFF_WW : OFF_ZZ);

  const int row = blockIdx.x * 64 + (tid >> 2);
  const int q = tid & 3;
  const float* sp = S + (size_t)row * D_DIM + q * 128;
  const size_t tbase = (size_t)(row >> 7) * 16 * 4096 + (size_t)(row & 127) * 8;

  float4 ssv = {0.f, 0.f, 0.f, 0.f};
#pragma unroll
  for (int c = 0; c < 16; c++) {
    const float4 x = *(const float4*)&sp[c * 8];
    const float4 y = *(const float4*)&sp[c * 8 + 4];
    ssv.x += x.x * x.x; ssv.y += x.y * x.y; ssv.z += x.z * x.z; ssv.w += x.w * x.w;
    ssv.x += y.x * y.x; ssv.y += y.y * y.y; ssv.z += y.z * y.z; ssv.w += y.w * y.w;
    f16x8 hv;
    hv[0] = (_Float16)(x.x * scale); hv[1] = (_Float16)(x.y * scale);
    hv[2] = (_Float16)(x.z * scale); hv[3] = (_Float16)(x.w * scale);
    hv[4] = (_Float16)(y.x * scale); hv[5] = (_Float16)(y.y * scale);
    hv[6] = (_Float16)(y.z * scale); hv[7] = (_Float16)(y.w * scale);
    const int d = q * 128 + c * 8;
    const int dt = d >> 5;
    const int chunk = (d >> 3) & 3;
    *(f16x8*)&H[tbase + (size_t)dt * 4096 + (size_t)chunk * 1024] = hv;
  }
  float s = (ssv.x + ssv.y) + (ssv.z + ssv.w);
  s += __shfl_xor(s, 1, 64);
  s += __shfl_xor(s, 2, 64);
  if (q == 0) norm[row] = s;
}

// ---- stage 1: screen. all-reg, dbuf register prefetch, XCD super-tile swizzle ----
// grid 4096 linear, block 256 (4 waves 2x2: wr=code-half, wc=zrow-half).
__global__ __launch_bounds__(256, 2) void vq_screen_kernel(
    const unsigned short* __restrict__ zh_s, const unsigned short* __restrict__ wh_s,
    const float* __restrict__ ww,
    float* __restrict__ bestd2, int* __restrict__ besti2) {
  const int tid = threadIdx.x;
  // bijective swizzle: each XCD owns 8x8 super-tiles (W 1MB + Z 1MB < 4MB L2)
  const int bid = blockIdx.x;
  const int xcd = bid & 7;
  const int j = bid >> 3;              // 0..511
  const int stid = xcd * 8 + (j >> 6); // 0..63 super-tile id
  const int wi = j & 63;
  const int cb = (stid & 7) * 8 + (wi & 7);
  const int rb = (stid >> 3) * 8 + (wi >> 3);

  const int lane = tid & 63, wv = tid >> 6;
  const int wr = wv >> 1, wc = wv & 1;
  const int lrow = lane & 31, lhi = lane >> 5;

  const f16x8* zh8 = (const f16x8*)zh_s;
  const f16x8* wh8 = (const f16x8*)wh_s;
  const int wbase = wr * 64 + lrow;
  const int zbase = wc * 64 + lrow;

  // acc[rf][cf]: A=W (code = wr*64+rf*32+(reg&3)+8*(reg>>2)+4*lhi),
  //             B=Z (zrow = wc*64+cf*32+lrow)
  f32x16 acc[2][2];
#pragma unroll
  for (int i = 0; i < 2; i++)
#pragma unroll
    for (int jj = 0; jj < 2; jj++)
#pragma unroll
      for (int e = 0; e < 16; e++) acc[i][jj][e] = 0.0f;

  f16x8 wA[4], zA[4], wB[4], zB[4];

#define LOADB(WX, ZX, dt) { \
    const int wt_ = (cb * 16 + (dt)) * 512; \
    const int zt_ = (rb * 16 + (dt)) * 512; \
    _Pragma("unroll") \
    for (int ks = 0; ks < 2; ks++) { \
      const int ch_ = ks * 2 + lhi; \
      WX[ks*2+0] = wh8[wt_ + ch_*128 + wbase]; \
      WX[ks*2+1] = wh8[wt_ + ch_*128 + wbase + 32]; \
      ZX[ks*2+0] = zh8[zt_ + ch_*128 + zbase]; \
      ZX[ks*2+1] = zh8[zt_ + ch_*128 + zbase + 32]; \
    } }

#define COMPUTEB(WX, ZX) { \
    __builtin_amdgcn_s_setprio(1); \
    _Pragma("unroll") \
    for (int ks = 0; ks < 2; ks++) { \
      acc[0][0] = MFMA16(WX[ks*2+0], ZX[ks*2+0], acc[0][0]); \
      acc[0][1] = MFMA16(WX[ks*2+0], ZX[ks*2+1], acc[0][1]); \
      acc[1][0] = MFMA16(WX[ks*2+1], ZX[ks*2+0], acc[1][0]); \
      acc[1][1] = MFMA16(WX[ks*2+1], ZX[ks*2+1], acc[1][1]); \
    } \
    __builtin_amdgcn_s_setprio(0); }

  LOADB(wA, zA, 0);
#pragma unroll
  for (int dtp = 0; dtp < 8; dtp++) {
    LOADB(wB, zB, dtp * 2 + 1);   // prefetch next dt before computing current
    COMPUTEB(wA, zA);
    if (dtp < 7) LOADB(wA, zA, dtp * 2 + 2);
    COMPUTEB(wB, zB);
  }
#undef LOADB
#undef COMPUTEB

  // epilogue: per lane in-register top-2 over its 32 codes, then one xor-32 merge.
  // acc = dot(z, w*8192); d~ = ww - 2*dot = fmaf(acc, -2^-12, ww)
#pragma unroll
  for (int cf = 0; cf < 2; cf++) {
    float p1d = 3.4e38f, p2d = 3.4e38f;
    int   p1i = 0x7fffffff, p2i = 0x7fffffff;
#pragma unroll
    for (int rf = 0; rf < 2; rf++) {
      const int cbase = cb * 128 + wr * 64 + rf * 32 + 4 * lhi;
#pragma unroll
      for (int reg = 0; reg < 16; reg++) {
        const int ci = cbase + (reg & 3) + 8 * (reg >> 2);
        const float d = fmaf(acc[rf][cf][reg], -2.44140625e-4f, ww[ci]);
        const bool b1 = d < p1d;
        const bool b2 = d < p2d;
        p2d = b1 ? p1d : (b2 ? d : p2d);
        p2i = b1 ? p1i : (b2 ? ci : p2i);
        p1d = b1 ? d : p1d;
        p1i = b1 ? ci : p1i;
      }
    }
    const float q1d = __shfl_xor(p1d, 32, 64); const int q1i = __shfl_xor(p1i, 32, 64);
    const float q2d = __shfl_xor(p2d, 32, 64); const int q2i = __shfl_xor(p2i, 32, 64);
    float t1d, t2d; int t1i, t2i;
    if (q1d < p1d) {
      t1d = q1d; t1i = q1i;
      if (p1d < q2d) { t2d = p1d; t2i = p1i; } else { t2d = q2d; t2i = q2i; }
    } else {
      t1d = p1d; t1i = p1i;
      if (q1d < p2d) { t2d = q1d; t2i = q1i; } else { t2d = p2d; t2i = p2i; }
    }
    if (lhi == 0) {
      const int row = rb * 128 + wc * 64 + cf * 32 + lrow;
      const size_t o = (size_t)row * 256 + (size_t)(cb * 2 + wr) * 2;
      float2 dv2; dv2.x = t1d; dv2.y = t2d;
      int2   iv2; iv2.x = t1i; iv2.y = t2i;
      *(float2*)&bestd2[o] = dv2;
      *(int2*)&besti2[o]   = iv2;
    }
  }
}

// ---- stage 2: rescore survivors exactly + outputs. one wave per row ----
__global__ __launch_bounds__(256) void vq_rescore_kernel(
    const float* __restrict__ z, const float* __restrict__ W,
    const float* __restrict__ zz, const float* __restrict__ ww,
    const float* __restrict__ bestd2, const int* __restrict__ besti2,
    float* __restrict__ out, float* __restrict__ ws_f) {
  const int row  = (blockIdx.x * 256 + threadIdx.x) >> 6;
  const int lane = threadIdx.x & 63;
  const size_t base = (size_t)row * 256;
  const float4 dv = *(const float4*)&bestd2[base + lane * 4];
  const int4  iv = *(const int4*)&besti2[base + lane * 4];
  float dd[4] = {dv.x, dv.y, dv.z, dv.w};
  int   ii[4] = {iv.x, iv.y, iv.z, iv.w};

  float m = fminf(fminf(dd[0], dd[1]), fminf(dd[2], dd[3]));
#pragma unroll
  for (int mm = 1; mm <= 32; mm <<= 1) m = fminf(m, __shfl_xor(m, mm, 64));
  const float thr = m + EPS;

  const float* zp = z + (size_t)row * D_DIM;
  const float4 za = *(const float4*)&zp[lane * 8];
  const float4 zb = *(const float4*)&zp[lane * 8 + 4];
  const float zzr = zz[row];

  float bd = 3.4e38f; int bi = 0x7fffffff;
#pragma unroll
  for (int s = 0; s < 4; s++) {
    unsigned long long mset = __ballot(dd[s] <= thr);
    while (mset) {
      const int b = __ffsll((long long)mset) - 1;
      mset &= mset - 1;
      const int c = __shfl(ii[s], b, 64);
      const float* wp = W + (size_t)c * D_DIM;
      const float4 wa = *(const float4*)&wp[lane * 8];
      const float4 wb = *(const float4*)&wp[lane * 8 + 4];
      float dot = za.x*wa.x + za.y*wa.y + za.z*wa.z + za.w*wa.w
                + zb.x*wb.x + zb.y*wb.y + zb.z*wb.z + zb.w*wb.w;
#pragma unroll
      for (int mm = 1; mm <= 32; mm <<= 1) dot += __shfl_xor(dot, mm, 64);
      // exact reference rounding: (zz - 2*dot) + ww
      const float dist = (zzr - 2.0f * dot) + ww[c];
      if (dist < bd || (dist == bd && c < bi)) { bd = dist; bi = c; }
    }
  }

  if (lane == 0) {
    out[(size_t)N_ROWS * D_DIM + row] = (float)bi;
    atomicAdd(&ws_f[OFF_COUNTS + bi], 1.0f);  // integer-valued: order-independent
  }
  // quantize + loss (proven gather body)
  const float* wp = W + (size_t)bi * D_DIM;
  float* op = out + (size_t)row * D_DIM;
  float lsum = 0.f;
#pragma unroll
  for (int h = 0; h < 2; h++) {
    const int dd2 = h * 256 + lane * 4;
    const float4 zv = *(const float4*)&zp[dd2];
    const float4 wv = *(const float4*)&wp[dd2];
    float4 q;
    q.x = zv.x + (wv.x - zv.x);
    q.y = zv.y + (wv.y - zv.y);
    q.z = zv.z + (wv.z - zv.z);
    q.w = zv.w + (wv.w - zv.w);
    *(float4*)&op[dd2] = q;
    float dx;
    dx = zv.x - wv.x; lsum += dx * dx;
    dx = zv.y - wv.y; lsum += dx * dx;
    dx = zv.z - wv.z; lsum += dx * dx;
    dx = zv.w - wv.w; lsum += dx * dx;
  }
#pragma unroll
  for (int off = 32; off > 0; off >>= 1) lsum += __shfl_down(lsum, off, 64);
  __shared__ float lred[4];
  if (lane == 0) lred[threadIdx.x >> 6] = lsum;
  __syncthreads();
  if (threadIdx.x == 0)
    ws_f[OFF_PARTIAL + blockIdx.x] = lred[0] + lred[1] + lred[2] + lred[3];
}

// ================= fallback fp32 path (round-1, proven) =================
__global__ __launch_bounds__(256) void rowss_kernel(const float* __restrict__ src,
                                                    float* __restrict__ dst) {
  int row  = (blockIdx.x * 256 + threadIdx.x) >> 6;
  int lane = threadIdx.x & 63;
  const float* p = src + (size_t)row * D_DIM;
  float4 a = *(const float4*)&p[lane * 4];
  float4 b = *(const float4*)&p[256 + lane * 4];
  float s = a.x*a.x + a.y*a.y + a.z*a.z + a.w*a.w
          + b.x*b.x + b.y*b.y + b.z*b.z + b.w*b.w;
#pragma unroll
  for (int off = 32; off > 0; off >>= 1) s += __shfl_down(s, off, 64);
  if (lane == 0) dst[row] = s;
}

constexpr int BN = 64, BK = 64, BD = 32;
__global__ __launch_bounds__(256) void vq_dist_kernel(
    const float* __restrict__ z, const float* __restrict__ W,
    const float* __restrict__ zz, const float* __restrict__ ww,
    float* __restrict__ bestd_out, int* __restrict__ besti_out) {
  __shared__ float zs[BD][68];
  __shared__ float ws_[BD][68];
  __shared__ float rd[BN][16];
  __shared__ int   ri[BN][16];
  const int tid = threadIdx.x;
  const int tx = tid & 15;
  const int ty = tid >> 4;
  const int r0 = blockIdx.x * BN;
  const int kbase0 = blockIdx.y * KSPL;
  const int lr = tid >> 3;
  const int lc = tid & 7;
  float bd[4]; int bi[4];
#pragma unroll
  for (int i = 0; i < 4; i++) { bd[i] = 3.4e38f; bi[i] = 0x7fffffff; }
  float zzr[4];
#pragma unroll
  for (int i = 0; i < 4; i++) zzr[i] = zz[r0 + ty * 4 + i];
  for (int kt = 0; kt < KSPL; kt += BK) {
    const int kb = kbase0 + kt;
    float c[4][4];
#pragma unroll
    for (int i = 0; i < 4; i++)
#pragma unroll
      for (int jj = 0; jj < 4; jj++) c[i][jj] = 0.f;
    for (int dtt = 0; dtt < D_DIM; dtt += BD) {
#pragma unroll
      for (int h = 0; h < 2; h++) {
        const int r = lr + h * 32;
        const float4 v = *(const float4*)&z[(size_t)(r0 + r) * D_DIM + dtt + lc * 4];
        zs[lc*4+0][r] = v.x; zs[lc*4+1][r] = v.y; zs[lc*4+2][r] = v.z; zs[lc*4+3][r] = v.w;
        const float4 u = *(const float4*)&W[(size_t)(kb + r) * D_DIM + dtt + lc * 4];
        ws_[lc*4+0][r] = u.x; ws_[lc*4+1][r] = u.y; ws_[lc*4+2][r] = u.z; ws_[lc*4+3][r] = u.w;
      }
      __syncthreads();
#pragma unroll
      for (int d = 0; d < BD; d++) {
        const float4 a = *(const float4*)&zs[d][ty * 4];
        const float4 b = *(const float4*)&ws_[d][tx * 4];
        c[0][0] += a.x*b.x; c[0][1] += a.x*b.y; c[0][2] += a.x*b.z; c[0][3] += a.x*b.w;
        c[1][0] += a.y*b.x; c[1][1] += a.y*b.y; c[1][2] += a.y*b.z; c[1][3] += a.y*b.w;
        c[2][0] += a.z*b.x; c[2][1] += a.z*b.y; c[2][2] += a.z*b.z; c[2][3] += a.z*b.w;
        c[3][0] += a.w*b.x; c[3][1] += a.w*b.y; c[3][2] += a.w*b.z; c[3][3] += a.w*b.w;
      }
      __syncthreads();
    }
#pragma unroll
    for (int i = 0; i < 4; i++) {
#pragma unroll
      for (int jj = 0; jj < 4; jj++) {
        const int col = kb + tx * 4 + jj;
        const float dist = (zzr[i] - 2.0f * c[i][jj]) + ww[col];
        if (dist < bd[i]) { bd[i] = dist; bi[i] = col; }
      }
    }
  }
#pragma unroll
  for (int i = 0; i < 4; i++) { rd[ty * 4 + i][tx] = bd[i]; ri[ty * 4 + i][tx] = bi[i]; }
  __syncthreads();
  if (tid < BN) {
    float best = rd[tid][0]; int bidx = ri[tid][0];
#pragma unroll
    for (int t = 1; t < 16; t++) {
      const float dv = rd[tid][t]; const int iv = ri[tid][t];
      if (dv < best || (dv == best && iv < bidx)) { best = dv; bidx = iv; }
    }
    bestd_out[(size_t)blockIdx.y * N_ROWS + r0 + tid] = best;
    besti_out[(size_t)blockIdx.y * N_ROWS + r0 + tid] = bidx;
  }
}

__global__ __launch_bounds__(256) void vq_gather8_kernel(
    const float* __restrict__ z, const float* __restrict__ W,
    const float* __restrict__ bestd, const int* __restrict__ besti,
    float* __restrict__ out, float* __restrict__ ws_f) {
  const int row  = (blockIdx.x * 256 + threadIdx.x) >> 6;
  const int lane = threadIdx.x & 63;
  int bidx = 0;
  if (lane == 0) {
    float best = bestd[row];
    bidx = besti[row];
#pragma unroll
    for (int s = 1; s < SPLITK; s++) {
      const float dv = bestd[(size_t)s * N_ROWS + row];
      const int iv = besti[(size_t)s * N_ROWS + row];
      if (dv < best || (dv == best && iv < bidx)) { best = dv; bidx = iv; }
    }
    out[(size_t)N_ROWS * D_DIM + row] = (float)bidx;
    atomicAdd(&ws_f[OFF_COUNTS + bidx], 1.0f);
  }
  bidx = __shfl(bidx, 0, 64);
  const float* zp = z + (size_t)row * D_DIM;
  const float* wp = W + (size_t)bidx * D_DIM;
  float* op = out + (size_t)row * D_DIM;
  float lsum = 0.f;
#pragma unroll
  for (int h = 0; h < 2; h++) {
    const int d = h * 256 + lane * 4;
    const float4 zv = *(const float4*)&zp[d];
    const float4 wv = *(const float4*)&wp[d];
    float4 q;
    q.x = zv.x + (wv.x - zv.x);
    q.y = zv.y + (wv.y - zv.y);
    q.z = zv.z + (wv.z - zv.z);
    q.w = zv.w + (wv.w - zv.w);
    *(float4*)&op[d] = q;
    float dx;
    dx = zv.x - wv.x; lsum += dx * dx;
    dx = zv.y - wv.y; lsum += dx * dx;
    dx = zv.z - wv.z; lsum += dx * dx;
    dx = zv.w - wv.w; lsum += dx * dx;
  }
#pragma unroll
  for (int off = 32; off > 0; off >>= 1) lsum += __shfl_down(lsum, off, 64);
  if (lane == 0) atomicAdd(&ws_f[OFF_LOSS], lsum);
}

// ---- finalize: loss scalar + perplexity ----
__global__ __launch_bounds__(256) void vq_finalize_kernel(const float* __restrict__ ws_f,
                                                          float* __restrict__ out,
                                                          int use_partial) {
  const int tid = threadIdx.x;
  float ls = 0.f;
  if (use_partial) {
    for (int i = tid; i < 2048; i += 256) ls += ws_f[OFF_PARTIAL + i];
  }
  float s = 0.f;
  for (int k = tid; k < K_CODES; k += 256) {
    const float p = ws_f[OFF_COUNTS + k] * (1.0f / 8192.0f);
    s += p * logf(p + 1e-10f);
  }
#pragma unroll
  for (int off = 32; off > 0; off >>= 1) {
    s  += __shfl_down(s, off, 64);
    ls += __shfl_down(ls, off, 64);
  }
  __shared__ float red[4], redl[4];
  if ((tid & 63) == 0) { red[tid >> 6] = s; redl[tid >> 6] = ls; }
  __syncthreads();
  if (tid == 0) {
    const float tot = red[0] + red[1] + red[2] + red[3];
    const float L = use_partial ? (redl[0] + redl[1] + redl[2] + redl[3])
                                : ws_f[OFF_LOSS];
    out[(size_t)N_ROWS * D_DIM + N_ROWS]     = COMMIT * (L / 4194304.0f);
    out[(size_t)N_ROWS * D_DIM + N_ROWS + 1] = expf(-tot);
  }
}

extern "C" void kernel_launch(void* const* d_in, const int* in_sizes, int n_in,
                              void* d_out, int out_size, void* d_ws, size_t ws_size,
                              hipStream_t stream) {
  const float* z = (const float*)d_in[0];
  const float* W = (const float*)d_in[1];
  float* out = (float*)d_out;
  float* ws_f = (float*)d_ws;
  int* ws_i = (int*)d_ws;

  if (ws_size >= WS_NEED) {
    unsigned short* zh = (unsigned short*)((char*)d_ws + F16_BASE_BYTES);
    unsigned short* wh = zh + SPLIT_ELEMS;
    prep_kernel<<<dim3(128, 2), 256, 0, stream>>>(z, W, zh, wh, ws_f);
    vq_screen_kernel<<<4096, 256, 0, stream>>>(
        zh, wh, ws_f + OFF_WW, ws_f + OFF_BESTD, ws_i + OFF_BESTI);
    vq_rescore_kernel<<<N_ROWS / 4, 256, 0, stream>>>(
        z, W, ws_f + OFF_ZZ, ws_f + OFF_WW,
        ws_f + OFF_BESTD, ws_i + OFF_BESTI, out, ws_f);
    vq_finalize_kernel<<<1, 256, 0, stream>>>(ws_f, out, 1);
  } else {
    hipMemsetAsync(d_ws, 0, (OFF_COUNTS + K_CODES) * sizeof(float), stream);
    rowss_kernel<<<N_ROWS / 4, 256, 0, stream>>>(z, ws_f + OFF_ZZ);
    rowss_kernel<<<K_CODES / 4, 256, 0, stream>>>(W, ws_f + OFF_WW);
    dim3 grid(N_ROWS / BN, SPLITK);
    vq_dist_kernel<<<grid, 256, 0, stream>>>(z, W, ws_f + OFF_ZZ, ws_f + OFF_WW,
                                             ws_f + OFF_BESTD, ws_i + OFF_BESTI);
    vq_gather8_kernel<<<N_ROWS / 4, 256, 0, stream>>>(z, W, ws_f + OFF_BESTD,
                                                      ws_i + OFF_BESTI, out, ws_f);
    vq_finalize_kernel<<<1, 256, 0, stream>>>(ws_f, out, 0);
  }
}

// Round 9
// 199.504 us; speedup vs baseline: 5.8651x; 1.0862x over previous
//
#include <hip/hip_runtime.h>
#include <math.h>

// VQ-VAE eval forward: z [4,2048,512] f32, W [8192,512] f32.
// Outputs (flat f32): quantized [4194304], indices [8192], loss [1], perplexity [1].
//
// Fast path (two-stage):
//   0) prep: fused zero + row-norms + f32->f16 tiling for z and W (1 kernel).
//   1) screen: f16 hh-only MFMA GEMM, all-register, 64x128 acc per wave
//      (intensity 21 FLOP/B vs TA roofline); top-2 per (row, 64 codes).
//   2) rescore: exact fp32 reference-rounded distance for all candidates within
//      EPS of the row's approx min; fused with quantize/loss/counts outputs.
// Fallback: round-1 fp32 VALU kernel (correctness-proven).

typedef __attribute__((ext_vector_type(8))) _Float16 f16x8;
typedef __attribute__((ext_vector_type(16))) float f32x16;

constexpr int N_ROWS = 8192;   // 4*2048
constexpr int K_CODES = 8192;
constexpr int D_DIM = 512;
constexpr float COMMIT = 0.25f;
// screen-vs-reference pairwise offset bound ~1.9e-4 (f16 hh error 3.2e-5 + fl
// quantization 6.1e-5, pairwise x2); EPS = 3e-4 gives >1.5x margin while
// keeping expected survivors ~1.1/row.
constexpr float EPS = 3.0e-4f;

// ---- workspace layout (float offsets) ----
constexpr size_t OFF_LOSS    = 0;
constexpr size_t OFF_COUNTS  = 64;         // 8192 floats
constexpr size_t OFF_PARTIAL = 8256;       // 2048 floats (per-block loss partials)
constexpr size_t OFF_ZZ      = 16384;      // 8192 floats
constexpr size_t OFF_WW      = 24576;      // 8192 floats
constexpr size_t OFF_BESTD   = 32768;      // fast: [8192 rows][256]; fallback: [8][8192]
constexpr size_t OFF_BESTI   = 2129920;    // ints, same shapes
constexpr size_t F16_BASE_BYTES = 16908288; // = (2129920 + 2097152) * 4
constexpr size_t SPLIT_ELEMS = (size_t)8192 * 512;
constexpr size_t SPLIT_BYTES = SPLIT_ELEMS * 2;           // 8 MB each
constexpr size_t WS_NEED = F16_BASE_BYTES + 2 * SPLIT_BYTES; // 33,685,504 B

constexpr int SPLITK = 8;
constexpr int KSPL = K_CODES / SPLITK;

#define MFMA16(a, b, c) __builtin_amdgcn_mfma_f32_32x32x16_f16((a), (b), (c), 0, 0, 0)

// ---- fast-path prep: zero ws accumulators + row sum-of-squares + f16 tiles ----
// grid (128, 2): x = 64-row block, y = src (0=z scale 1, 1=W scale 8192).
// 256 threads: row = bx*64 + (tid>>2); q = tid&3 covers dims [q*128, q*128+128).
__global__ __launch_bounds__(256) void prep_kernel(
    const float* __restrict__ z, const float* __restrict__ W,
    unsigned short* __restrict__ zh, unsigned short* __restrict__ wh,
    float* __restrict__ ws_f) {
  const int src = blockIdx.y;
  const int tid = threadIdx.x;
  // zero [0, 10304) floats: loss + counts + partials (disjoint from ZZ/WW)
  if (src == 0 && blockIdx.x < 11) {
#pragma unroll
    for (int k = 0; k < 4; k++) {
      const int idx = blockIdx.x * 1024 + k * 256 + tid;
      if (idx < 10304) ws_f[idx] = 0.0f;
    }
  }
  const float* S = src ? W : z;
  unsigned short* H = src ? wh : zh;
  const float scale = src ? 8192.0f : 1.0f;
  float* norm = ws_f + (src ? OFF_WW : OFF_ZZ);

  const int row = blockIdx.x * 64 + (tid >> 2);
  const int q = tid & 3;
  const float* sp = S + (size_t)row * D_DIM + q * 128;
  const size_t tbase = (size_t)(row >> 7) * 16 * 4096 + (size_t)(row & 127) * 8;

  float4 ssv = {0.f, 0.f, 0.f, 0.f};
#pragma unroll
  for (int c = 0; c < 16; c++) {
    const float4 x = *(const float4*)&sp[c * 8];
    const float4 y = *(const float4*)&sp[c * 8 + 4];
    ssv.x += x.x * x.x; ssv.y += x.y * x.y; ssv.z += x.z * x.z; ssv.w += x.w * x.w;
    ssv.x += y.x * y.x; ssv.y += y.y * y.y; ssv.z += y.z * y.z; ssv.w += y.w * y.w;
    f16x8 hv;
    hv[0] = (_Float16)(x.x * scale); hv[1] = (_Float16)(x.y * scale);
    hv[2] = (_Float16)(x.z * scale); hv[3] = (_Float16)(x.w * scale);
    hv[4] = (_Float16)(y.x * scale); hv[5] = (_Float16)(y.y * scale);
    hv[6] = (_Float16)(y.z * scale); hv[7] = (_Float16)(y.w * scale);
    const int d = q * 128 + c * 8;
    const int dt = d >> 5;
    const int chunk = (d >> 3) & 3;
    *(f16x8*)&H[tbase + (size_t)dt * 4096 + (size_t)chunk * 1024] = hv;
  }
  float s = (ssv.x + ssv.y) + (ssv.z + ssv.w);
  s += __shfl_xor(s, 1, 64);
  s += __shfl_xor(s, 2, 64);
  if (q == 0) norm[row] = s;
}

// ---- stage 1: screen. all-register, 64x128 acc/wave, top-2 per (row, 64 codes) ----
// grid 2048 linear (cb = bid&63: 128-code block, rb = bid>>6: 256-zrow block),
// block 256 (4 waves 2x2: wr = 64-code half, wc = 128-zrow half).
__global__ __launch_bounds__(256, 2) void vq_screen_kernel(
    const unsigned short* __restrict__ zh_s, const unsigned short* __restrict__ wh_s,
    const float* __restrict__ ww,
    float* __restrict__ bestd2, int* __restrict__ besti2) {
  const int tid = threadIdx.x;
  const int bid = blockIdx.x;
  const int cb = bid & 63;    // 64 code-blocks of 128
  const int rb = bid >> 6;    // 32 zrow-blocks of 256

  const int lane = tid & 63, wv = tid >> 6;
  const int wr = wv >> 1, wc = wv & 1;
  const int lrow = lane & 31, lhi = lane >> 5;

  const f16x8* zh8 = (const f16x8*)zh_s;
  const f16x8* wh8 = (const f16x8*)wh_s;
  const int wbase = wr * 64 + lrow;
  const int ztile = rb * 2 + wc;  // wc*128 zrows == exactly one 128-row tile

  // acc[rf][cf]: A=W (code = cb*128 + wr*64 + rf*32 + (reg&3)+8*(reg>>2)+4*lhi),
  //             B=Z (zrow = rb*256 + wc*128 + cf*32 + lrow)
  f32x16 acc[2][4];
#pragma unroll
  for (int i = 0; i < 2; i++)
#pragma unroll
    for (int jj = 0; jj < 4; jj++)
#pragma unroll
      for (int e = 0; e < 16; e++) acc[i][jj][e] = 0.0f;

#pragma unroll 2
  for (int dt = 0; dt < 16; dt++) {
    const int wt_ = (cb * 16 + dt) * 512;   // f16x8 units
    const int zt_ = (ztile * 16 + dt) * 512;
    f16x8 wf[2][2], zf[2][4];
#pragma unroll
    for (int ks = 0; ks < 2; ks++) {
      const int ch = ks * 2 + lhi;
      wf[ks][0] = wh8[wt_ + ch * 128 + wbase];
      wf[ks][1] = wh8[wt_ + ch * 128 + wbase + 32];
#pragma unroll
      for (int cf = 0; cf < 4; cf++)
        zf[ks][cf] = zh8[zt_ + ch * 128 + cf * 32 + lrow];
    }
    __builtin_amdgcn_s_setprio(1);
#pragma unroll
    for (int ks = 0; ks < 2; ks++)
#pragma unroll
      for (int cf = 0; cf < 4; cf++) {
        acc[0][cf] = MFMA16(wf[ks][0], zf[ks][cf], acc[0][cf]);
        acc[1][cf] = MFMA16(wf[ks][1], zf[ks][cf], acc[1][cf]);
      }
    __builtin_amdgcn_s_setprio(0);
  }

  // epilogue: per lane in-register top-2 over its 32 codes, then one xor-32 merge.
  // acc = dot(z, w*8192); d~ = ww - 2*dot = fmaf(acc, -2^-12, ww)
#pragma unroll
  for (int cf = 0; cf < 4; cf++) {
    float p1d = 3.4e38f, p2d = 3.4e38f;
    int   p1i = 0x7fffffff, p2i = 0x7fffffff;
#pragma unroll
    for (int rf = 0; rf < 2; rf++) {
      const int cbase = cb * 128 + wr * 64 + rf * 32 + 4 * lhi;
#pragma unroll
      for (int reg = 0; reg < 16; reg++) {
        const int ci = cbase + (reg & 3) + 8 * (reg >> 2);
        const float d = fmaf(acc[rf][cf][reg], -2.44140625e-4f, ww[ci]);
        const bool b1 = d < p1d;
        const bool b2 = d < p2d;
        p2d = b1 ? p1d : (b2 ? d : p2d);
        p2i = b1 ? p1i : (b2 ? ci : p2i);
        p1d = b1 ? d : p1d;
        p1i = b1 ? ci : p1i;
      }
    }
    const float q1d = __shfl_xor(p1d, 32, 64); const int q1i = __shfl_xor(p1i, 32, 64);
    const float q2d = __shfl_xor(p2d, 32, 64); const int q2i = __shfl_xor(p2i, 32, 64);
    float t1d, t2d; int t1i, t2i;
    if (q1d < p1d) {
      t1d = q1d; t1i = q1i;
      if (p1d < q2d) { t2d = p1d; t2i = p1i; } else { t2d = q2d; t2i = q2i; }
    } else {
      t1d = p1d; t1i = p1i;
      if (q1d < p2d) { t2d = q1d; t2i = q1i; } else { t2d = p2d; t2i = p2i; }
    }
    if (lhi == 0) {
      const int row = rb * 256 + wc * 128 + cf * 32 + lrow;
      const size_t o = (size_t)row * 256 + (size_t)(cb * 2 + wr) * 2;
      float2 dv2; dv2.x = t1d; dv2.y = t2d;
      int2   iv2; iv2.x = t1i; iv2.y = t2i;
      *(float2*)&bestd2[o] = dv2;
      *(int2*)&besti2[o]   = iv2;
    }
  }
}

// ---- stage 2: rescore survivors exactly + outputs. one wave per row ----
__global__ __launch_bounds__(256) void vq_rescore_kernel(
    const float* __restrict__ z, const float* __restrict__ W,
    const float* __restrict__ zz, const float* __restrict__ ww,
    const float* __restrict__ bestd2, const int* __restrict__ besti2,
    float* __restrict__ out, float* __restrict__ ws_f) {
  const int row  = (blockIdx.x * 256 + threadIdx.x) >> 6;
  const int lane = threadIdx.x & 63;
  const size_t base = (size_t)row * 256;
  const float4 dv = *(const float4*)&bestd2[base + lane * 4];
  const int4  iv = *(const int4*)&besti2[base + lane * 4];
  float dd[4] = {dv.x, dv.y, dv.z, dv.w};
  int   ii[4] = {iv.x, iv.y, iv.z, iv.w};

  float m = fminf(fminf(dd[0], dd[1]), fminf(dd[2], dd[3]));
#pragma unroll
  for (int mm = 1; mm <= 32; mm <<= 1) m = fminf(m, __shfl_xor(m, mm, 64));
  const float thr = m + EPS;

  const float* zp = z + (size_t)row * D_DIM;
  const float4 za = *(const float4*)&zp[lane * 8];
  const float4 zb = *(const float4*)&zp[lane * 8 + 4];
  const float zzr = zz[row];

  float bd = 3.4e38f; int bi = 0x7fffffff;
#pragma unroll
  for (int s = 0; s < 4; s++) {
    unsigned long long mset = __ballot(dd[s] <= thr);
    while (mset) {
      const int b = __ffsll((long long)mset) - 1;
      mset &= mset - 1;
      const int c = __shfl(ii[s], b, 64);
      const float* wp = W + (size_t)c * D_DIM;
      const float4 wa = *(const float4*)&wp[lane * 8];
      const float4 wb = *(const float4*)&wp[lane * 8 + 4];
      float dot = za.x*wa.x + za.y*wa.y + za.z*wa.z + za.w*wa.w
                + zb.x*wb.x + zb.y*wb.y + zb.z*wb.z + zb.w*wb.w;
#pragma unroll
      for (int mm = 1; mm <= 32; mm <<= 1) dot += __shfl_xor(dot, mm, 64);
      // exact reference rounding: (zz - 2*dot) + ww
      const float dist = (zzr - 2.0f * dot) + ww[c];
      if (dist < bd || (dist == bd && c < bi)) { bd = dist; bi = c; }
    }
  }

  if (lane == 0) {
    out[(size_t)N_ROWS * D_DIM + row] = (float)bi;
    atomicAdd(&ws_f[OFF_COUNTS + bi], 1.0f);  // integer-valued: order-independent
  }
  // quantize + loss (proven gather body)
  const float* wp = W + (size_t)bi * D_DIM;
  float* op = out + (size_t)row * D_DIM;
  float lsum = 0.f;
#pragma unroll
  for (int h = 0; h < 2; h++) {
    const int dd2 = h * 256 + lane * 4;
    const float4 zv = *(const float4*)&zp[dd2];
    const float4 wv = *(const float4*)&wp[dd2];
    float4 q;
    q.x = zv.x + (wv.x - zv.x);
    q.y = zv.y + (wv.y - zv.y);
    q.z = zv.z + (wv.z - zv.z);
    q.w = zv.w + (wv.w - zv.w);
    *(float4*)&op[dd2] = q;
    float dx;
    dx = zv.x - wv.x; lsum += dx * dx;
    dx = zv.y - wv.y; lsum += dx * dx;
    dx = zv.z - wv.z; lsum += dx * dx;
    dx = zv.w - wv.w; lsum += dx * dx;
  }
#pragma unroll
  for (int off = 32; off > 0; off >>= 1) lsum += __shfl_down(lsum, off, 64);
  __shared__ float lred[4];
  if (lane == 0) lred[threadIdx.x >> 6] = lsum;
  __syncthreads();
  if (threadIdx.x == 0)
    ws_f[OFF_PARTIAL + blockIdx.x] = lred[0] + lred[1] + lred[2] + lred[3];
}

// ================= fallback fp32 path (round-1, proven) =================
__global__ __launch_bounds__(256) void rowss_kernel(const float* __restrict__ src,
                                                    float* __restrict__ dst) {
  int row  = (blockIdx.x * 256 + threadIdx.x) >> 6;
  int lane = threadIdx.x & 63;
  const float* p = src + (size_t)row * D_DIM;
  float4 a = *(const float4*)&p[lane * 4];
  float4 b = *(const float4*)&p[256 + lane * 4];
  float s = a.x*a.x + a.y*a.y + a.z*a.z + a.w*a.w
          + b.x*b.x + b.y*b.y + b.z*b.z + b.w*b.w;
#pragma unroll
  for (int off = 32; off > 0; off >>= 1) s += __shfl_down(s, off, 64);
  if (lane == 0) dst[row] = s;
}

constexpr int BN = 64, BK = 64, BD = 32;
__global__ __launch_bounds__(256) void vq_dist_kernel(
    const float* __restrict__ z, const float* __restrict__ W,
    const float* __restrict__ zz, const float* __restrict__ ww,
    float* __restrict__ bestd_out, int* __restrict__ besti_out) {
  __shared__ float zs[BD][68];
  __shared__ float ws_[BD][68];
  __shared__ float rd[BN][16];
  __shared__ int   ri[BN][16];
  const int tid = threadIdx.x;
  const int tx = tid & 15;
  const int ty = tid >> 4;
  const int r0 = blockIdx.x * BN;
  const int kbase0 = blockIdx.y * KSPL;
  const int lr = tid >> 3;
  const int lc = tid & 7;
  float bd[4]; int bi[4];
#pragma unroll
  for (int i = 0; i < 4; i++) { bd[i] = 3.4e38f; bi[i] = 0x7fffffff; }
  float zzr[4];
#pragma unroll
  for (int i = 0; i < 4; i++) zzr[i] = zz[r0 + ty * 4 + i];
  for (int kt = 0; kt < KSPL; kt += BK) {
    const int kb = kbase0 + kt;
    float c[4][4];
#pragma unroll
    for (int i = 0; i < 4; i++)
#pragma unroll
      for (int jj = 0; jj < 4; jj++) c[i][jj] = 0.f;
    for (int dtt = 0; dtt < D_DIM; dtt += BD) {
#pragma unroll
      for (int h = 0; h < 2; h++) {
        const int r = lr + h * 32;
        const float4 v = *(const float4*)&z[(size_t)(r0 + r) * D_DIM + dtt + lc * 4];
        zs[lc*4+0][r] = v.x; zs[lc*4+1][r] = v.y; zs[lc*4+2][r] = v.z; zs[lc*4+3][r] = v.w;
        const float4 u = *(const float4*)&W[(size_t)(kb + r) * D_DIM + dtt + lc * 4];
        ws_[lc*4+0][r] = u.x; ws_[lc*4+1][r] = u.y; ws_[lc*4+2][r] = u.z; ws_[lc*4+3][r] = u.w;
      }
      __syncthreads();
#pragma unroll
      for (int d = 0; d < BD; d++) {
        const float4 a = *(const float4*)&zs[d][ty * 4];
        const float4 b = *(const float4*)&ws_[d][tx * 4];
        c[0][0] += a.x*b.x; c[0][1] += a.x*b.y; c[0][2] += a.x*b.z; c[0][3] += a.x*b.w;
        c[1][0] += a.y*b.x; c[1][1] += a.y*b.y; c[1][2] += a.y*b.z; c[1][3] += a.y*b.w;
        c[2][0] += a.z*b.x; c[2][1] += a.z*b.y; c[2][2] += a.z*b.z; c[2][3] += a.z*b.w;
        c[3][0] += a.w*b.x; c[3][1] += a.w*b.y; c[3][2] += a.w*b.z; c[3][3] += a.w*b.w;
      }
      __syncthreads();
    }
#pragma unroll
    for (int i = 0; i < 4; i++) {
#pragma unroll
      for (int jj = 0; jj < 4; jj++) {
        const int col = kb + tx * 4 + jj;
        const float dist = (zzr[i] - 2.0f * c[i][jj]) + ww[col];
        if (dist < bd[i]) { bd[i] = dist; bi[i] = col; }
      }
    }
  }
#pragma unroll
  for (int i = 0; i < 4; i++) { rd[ty * 4 + i][tx] = bd[i]; ri[ty * 4 + i][tx] = bi[i]; }
  __syncthreads();
  if (tid < BN) {
    float best = rd[tid][0]; int bidx = ri[tid][0];
#pragma unroll
    for (int t = 1; t < 16; t++) {
      const float dv = rd[tid][t]; const int iv = ri[tid][t];
      if (dv < best || (dv == best && iv < bidx)) { best = dv; bidx = iv; }
    }
    bestd_out[(size_t)blockIdx.y * N_ROWS + r0 + tid] = best;
    besti_out[(size_t)blockIdx.y * N_ROWS + r0 + tid] = bidx;
  }
}

__global__ __launch_bounds__(256) void vq_gather8_kernel(
    const float* __restrict__ z, const float* __restrict__ W,
    const float* __restrict__ bestd, const int* __restrict__ besti,
    float* __restrict__ out, float* __restrict__ ws_f) {
  const int row  = (blockIdx.x * 256 + threadIdx.x) >> 6;
  const int lane = threadIdx.x & 63;
  int bidx = 0;
  if (lane == 0) {
    float best = bestd[row];
    bidx = besti[row];
#pragma unroll
    for (int s = 1; s < SPLITK; s++) {
      const float dv = bestd[(size_t)s * N_ROWS + row];
      const int iv = besti[(size_t)s * N_ROWS + row];
      if (dv < best || (dv == best && iv < bidx)) { best = dv; bidx = iv; }
    }
    out[(size_t)N_ROWS * D_DIM + row] = (float)bidx;
    atomicAdd(&ws_f[OFF_COUNTS + bidx], 1.0f);
  }
  bidx = __shfl(bidx, 0, 64);
  const float* zp = z + (size_t)row * D_DIM;
  const float* wp = W + (size_t)bidx * D_DIM;
  float* op = out + (size_t)row * D_DIM;
  float lsum = 0.f;
#pragma unroll
  for (int h = 0; h < 2; h++) {
    const int d = h * 256 + lane * 4;
    const float4 zv = *(const float4*)&zp[d];
    const float4 wv = *(const float4*)&wp[d];
    float4 q;
    q.x = zv.x + (wv.x - zv.x);
    q.y = zv.y + (wv.y - zv.y);
    q.z = zv.z + (wv.z - zv.z);
    q.w = zv.w + (wv.w - zv.w);
    *(float4*)&op[d] = q;
    float dx;
    dx = zv.x - wv.x; lsum += dx * dx;
    dx = zv.y - wv.y; lsum += dx * dx;
    dx = zv.z - wv.z; lsum += dx * dx;
    dx = zv.w - wv.w; lsum += dx * dx;
  }
#pragma unroll
  for (int off = 32; off > 0; off >>= 1) lsum += __shfl_down(lsum, off, 64);
  if (lane == 0) atomicAdd(&ws_f[OFF_LOSS], lsum);
}

// ---- finalize: loss scalar + perplexity ----
__global__ __launch_bounds__(256) void vq_finalize_kernel(const float* __restrict__ ws_f,
                                                          float* __restrict__ out,
                                                          int use_partial) {
  const int tid = threadIdx.x;
  float ls = 0.f;
  if (use_partial) {
    for (int i = tid; i < 2048; i += 256) ls += ws_f[OFF_PARTIAL + i];
  }
  float s = 0.f;
  for (int k = tid; k < K_CODES; k += 256) {
    const float p = ws_f[OFF_COUNTS + k] * (1.0f / 8192.0f);
    s += p * logf(p + 1e-10f);
  }
#pragma unroll
  for (int off = 32; off > 0; off >>= 1) {
    s  += __shfl_down(s, off, 64);
    ls += __shfl_down(ls, off, 64);
  }
  __shared__ float red[4], redl[4];
  if ((tid & 63) == 0) { red[tid >> 6] = s; redl[tid >> 6] = ls; }
  __syncthreads();
  if (tid == 0) {
    const float tot = red[0] + red[1] + red[2] + red[3];
    const float L = use_partial ? (redl[0] + redl[1] + redl[2] + redl[3])
                                : ws_f[OFF_LOSS];
    out[(size_t)N_ROWS * D_DIM + N_ROWS]     = COMMIT * (L / 4194304.0f);
    out[(size_t)N_ROWS * D_DIM + N_ROWS + 1] = expf(-tot);
  }
}

extern "C" void kernel_launch(void* const* d_in, const int* in_sizes, int n_in,
                              void* d_out, int out_size, void* d_ws, size_t ws_size,
                              hipStream_t stream) {
  const float* z = (const float*)d_in[0];
  const float* W = (const float*)d_in[1];
  float* out = (float*)d_out;
  float* ws_f = (float*)d_ws;
  int* ws_i = (int*)d_ws;

  if (ws_size >= WS_NEED) {
    unsigned short* zh = (unsigned short*)((char*)d_ws + F16_BASE_BYTES);
    unsigned short* wh = zh + SPLIT_ELEMS;
    prep_kernel<<<dim3(128, 2), 256, 0, stream>>>(z, W, zh, wh, ws_f);
    vq_screen_kernel<<<2048, 256, 0, stream>>>(
        zh, wh, ws_f + OFF_WW, ws_f + OFF_BESTD, ws_i + OFF_BESTI);
    vq_rescore_kernel<<<N_ROWS / 4, 256, 0, stream>>>(
        z, W, ws_f + OFF_ZZ, ws_f + OFF_WW,
        ws_f + OFF_BESTD, ws_i + OFF_BESTI, out, ws_f);
    vq_finalize_kernel<<<1, 256, 0, stream>>>(ws_f, out, 1);
  } else {
    hipMemsetAsync(d_ws, 0, (OFF_COUNTS + K_CODES) * sizeof(float), stream);
    rowss_kernel<<<N_ROWS / 4, 256, 0, stream>>>(z, ws_f + OFF_ZZ);
    rowss_kernel<<<K_CODES / 4, 256, 0, stream>>>(W, ws_f + OFF_WW);
    dim3 grid(N_ROWS / BN, SPLITK);
    vq_dist_kernel<<<grid, 256, 0, stream>>>(z, W, ws_f + OFF_ZZ, ws_f + OFF_WW,
                                             ws_f + OFF_BESTD, ws_i + OFF_BESTI);
    vq_gather8_kernel<<<N_ROWS / 4, 256, 0, stream>>>(z, W, ws_f + OFF_BESTD,
                                                      ws_i + OFF_BESTI, out, ws_f);
    vq_finalize_kernel<<<1, 256, 0, stream>>>(ws_f, out, 0);
  }
}